// Round 10
// baseline (204.507 us; speedup 1.0000x reference)
//
#include <hip/hip_runtime.h>
#include <stdint.h>

#define N    4096
#define EMB  256
#define NH   4
#define HC   64     // channels per head
#define PAD  40     // LDS inner stride (elements): 80B = 20 banks -> <=2-way

typedef __attribute__((ext_vector_type(8))) short s16x8;   // 8 bf16 frag
typedef __attribute__((ext_vector_type(4))) short s16x4;
typedef __attribute__((ext_vector_type(4))) float f32x4;
typedef __attribute__((ext_vector_type(4))) int   i32x4;
typedef unsigned short ushort_t;

__device__ __forceinline__ unsigned short f2bf(float f) {
  unsigned int u = __builtin_bit_cast(unsigned int, f);
  u += 0x7fffu + ((u >> 16) & 1u);      // RNE (finite values only)
  return (unsigned short)(u >> 16);
}

// ---------------- K_prep: fused weight-transpose + adjacency bitmask -------
__global__ __launch_bounds__(256)
void k_prep(const float* __restrict__ W0, ushort_t* __restrict__ WP0,
            const float* __restrict__ W1, ushort_t* __restrict__ WP1,
            const int* __restrict__ adj, unsigned int* __restrict__ abits)
{
  int b = blockIdx.x;
  if (b < 1024) {
    const int w = threadIdx.x >> 6, lane = threadIdx.x & 63;
    const int i = b * 4 + w;
    const int* row = adj + (size_t)i * N;
    #pragma unroll 4
    for (int c = 0; c < 64; ++c) {
      int v = row[c * 64 + lane];
      unsigned long long m = __ballot(v != 0);
      if ((i >> 6) == c) m |= 1ull << (i & 63);
      if (lane == 0)      abits[(size_t)(2 * c)     * N + i] = (unsigned int)m;
      else if (lane == 1) abits[(size_t)(2 * c + 1) * N + i] = (unsigned int)(m >> 32);
    }
  } else {
    b -= 1024;
    int k = b & 255;
    int m = threadIdx.x;
    size_t dst = ((size_t)(k >> 5) * 256 + m) * 32 + (k & 31);
    if (b < 256) WP0[dst] = f2bf(W0[k * EMB + m]);
    else         WP1[dst] = f2bf(W1[k * EMB + m]);
  }
}

// ---------------- K1: h = x @ W_lin (bf16 MFMA), barrier-free K-loop -------
// A-frags direct from x (fp32->bf16 in regs); B-frags direct from L2-hot
// WlP k-panels. No LDS in the loop (R10: the 16-barrier K-loop was the
// hidden latency sink). Epilogue: hS fragment-tile store + a_src/a_dst.
__global__ __launch_bounds__(256, 2)
void k1_gemm_h(const float* __restrict__ x,
               const ushort_t* __restrict__ WlP,      // [8][256][32] k-panels
               const float* __restrict__ att_src,     // [4][64]
               const float* __restrict__ att_dst,
               ushort_t* __restrict__ hS,             // [4][128][64][32]
               float* __restrict__ a_srcT,            // [4][4096]
               float* __restrict__ a_dstT)
{
  __shared__ ushort_t T_lds[64][PAD];   // [c][node 0..31]
  __shared__ float red_lds[2][2][32];   // [src/dst][chalf][node]
  const int t = threadIdx.x;
  const int lane = t & 63;
  const int w = t >> 6;
  const int ihalf = w & 1, chalf = w >> 1;
  const int i0 = blockIdx.x * 32;
  const int head = blockIdx.y;
  const int c0 = head * 64;
  const int lq = lane >> 4, lm = lane & 15;

  f32x4 acc[2];
  acc[0] = f32x4{0.f, 0.f, 0.f, 0.f};
  acc[1] = f32x4{0.f, 0.f, 0.f, 0.f};

  const float* xrow = x + (size_t)(i0 + ihalf * 16 + lm) * EMB + lq * 8;
  const ushort_t* wp0 = WlP + (size_t)(c0 + chalf * 32 + lm) * 32 + lq * 8;
  const ushort_t* wp1 = WlP + (size_t)(c0 + chalf * 32 + 16 + lm) * 32 + lq * 8;

  #pragma unroll 2
  for (int kp = 0; kp < 8; ++kp) {
    f32x4 v0 = *(const f32x4*)(xrow + kp * 32);
    f32x4 v1 = *(const f32x4*)(xrow + kp * 32 + 4);
    s16x8 a;
    a[0]=(short)f2bf(v0[0]); a[1]=(short)f2bf(v0[1]); a[2]=(short)f2bf(v0[2]); a[3]=(short)f2bf(v0[3]);
    a[4]=(short)f2bf(v1[0]); a[5]=(short)f2bf(v1[1]); a[6]=(short)f2bf(v1[2]); a[7]=(short)f2bf(v1[3]);
    s16x8 b0 = *(const s16x8*)(wp0 + (size_t)kp * 8192);
    s16x8 b1 = *(const s16x8*)(wp1 + (size_t)kp * 8192);
    acc[0] = __builtin_amdgcn_mfma_f32_16x16x32_bf16(a, b0, acc[0], 0, 0, 0);
    acc[1] = __builtin_amdgcn_mfma_f32_16x16x32_bf16(a, b1, acc[1], 0, 0, 0);
  }

  float ps[4] = {0.f,0.f,0.f,0.f}, pd[4] = {0.f,0.f,0.f,0.f};
  #pragma unroll
  for (int nf = 0; nf < 2; ++nf) {
    int c = chalf * 32 + nf * 16 + lm;
    float wsv = att_src[c0 + c];
    float wdv = att_dst[c0 + c];
    #pragma unroll
    for (int r = 0; r < 4; ++r) {
      float v = acc[nf][r];                 // D: row=lq*4+r, col=lm
      T_lds[c][ihalf * 16 + lq * 4 + r] = f2bf(v);
      ps[r] += v * wsv;
      pd[r] += v * wdv;
    }
  }
  #pragma unroll
  for (int r = 0; r < 4; ++r) {
    #pragma unroll
    for (int mm = 1; mm < 16; mm <<= 1) {
      ps[r] += __shfl_xor(ps[r], mm);
      pd[r] += __shfl_xor(pd[r], mm);
    }
  }
  if (lm == 0) {
    #pragma unroll
    for (int r = 0; r < 4; ++r) {
      int node = ihalf * 16 + lq * 4 + r;
      red_lds[0][chalf][node] = ps[r];
      red_lds[1][chalf][node] = pd[r];
    }
  }
  __syncthreads();
  if (t < 32) {
    a_srcT[head * N + i0 + t] = red_lds[0][0][t] + red_lds[0][1][t];
    a_dstT[head * N + i0 + t] = red_lds[1][0][t] + red_lds[1][1][t];
  }
  {
    int c = t >> 2, seg = t & 3;
    s16x8 v = *(const s16x8*)&T_lds[c][seg * 8];
    size_t base = (((size_t)head * 128 + (i0 >> 5)) * 64 + c) * 32 + seg * 8;
    *(s16x8*)(hS + base) = v;
  }
}

// ---------------- K34: fused masked-softmax attention, atomic-free ---------
// R6-EXACT loop (proven 44us; VGPR 40): 512 thr = 8 waves = (2 heads x 4
// j-quarters), i-tile 16, grid (N/16, 2), unroll 2 (R9 lesson: unroll 3 ->
// VGPR 36, 56us — pragma knobs don't control scheduling; don't touch).
// Epilogue change only: write oS in fragment-tile layout [i/16][kp][16][32]
// so k5's A-loads are fully coalesced.
__global__ __launch_bounds__(512, 2)
void k34_attn(const unsigned int* __restrict__ abits, // [128 jw][4096 i]
              const ushort_t* __restrict__ hS,        // [4][128][64][32]
              const float* __restrict__ a_srcT,       // [4][4096]
              const float* __restrict__ a_dstT,       // [4][4096]
              const float* __restrict__ bias_att,     // [256]
              ushort_t* __restrict__ oS)              // [256][8][16][32]
{
  __shared__ float acc_lds[2][3][16][65];  // jq=1..3 partials per local head
  __shared__ float l_lds[2][4][16];

  const int t = threadIdx.x;
  const int lane = t & 63;
  const int w = t >> 6;            // 0..7
  const int hloc = w & 1;          // local head (of the pair)
  const int jq = w >> 1;           // j-quarter 0..3
  const int head = blockIdx.y * 2 + hloc;
  const int i0 = blockIdx.x * 16;
  const int lm = lane & 15, lq = lane >> 4;
  const int ig = i0 + lm;          // this lane's A-row (i)

  const float* asrc_h = a_srcT + head * N;
  const ushort_t* hS_h = hS + (size_t)head * 128 * 64 * 32;
  const float ad = a_dstT[head * N + ig];

  f32x4 acc[4];
  #pragma unroll
  for (int nf = 0; nf < 4; ++nf) acc[nf] = f32x4{0.f, 0.f, 0.f, 0.f};
  float lp = 0.f;

  #pragma unroll 2
  for (int it = 0; it < 32; ++it) {
    const int jw = jq * 32 + it;               // j-window (32 j's)
    const int jl = jw * 32 + lq * 8;           // this lane's first j

    unsigned int word = abits[(size_t)jw * N + ig];      // coalesced 64B
    f32x4 as0 = *(const f32x4*)(asrc_h + jl);
    f32x4 as1 = *(const f32x4*)(asrc_h + jl + 4);

    const ushort_t* tile = hS_h + (size_t)jw * 2048;     // [64 c][32 j]
    s16x8 b0 = *(const s16x8*)(tile + ( 0 + lm) * 32 + lq * 8);
    s16x8 b1 = *(const s16x8*)(tile + (16 + lm) * 32 + lq * 8);
    s16x8 b2 = *(const s16x8*)(tile + (32 + lm) * 32 + lq * 8);
    s16x8 b3 = *(const s16x8*)(tile + (48 + lm) * 32 + lq * 8);

    unsigned int ebits[8];
    #pragma unroll
    for (int jj = 0; jj < 8; ++jj) {
      float asv = (jj < 4) ? as0[jj] : as1[jj - 4];
      float sc = asv + ad;
      sc = fmaxf(sc, 0.2f * sc);                         // leaky relu
      bool con = (word >> (lq * 8 + jj)) & 1u;           // adj + self-loop
      float e = con ? __expf(sc) : 0.f;
      unsigned int eb = __builtin_bit_cast(unsigned int, e) & 0xffff0000u; // trunc bf16
      ebits[jj] = eb;
      lp += __builtin_bit_cast(float, eb);               // sum the SAME rounded value
    }
    i32x4 pk;
    #pragma unroll
    for (int u = 0; u < 4; ++u)
      pk[u] = (int)__builtin_amdgcn_perm(ebits[2 * u + 1], ebits[2 * u], 0x07060302u);
    s16x8 af = __builtin_bit_cast(s16x8, pk);

    acc[0] = __builtin_amdgcn_mfma_f32_16x16x32_bf16(af, b0, acc[0], 0, 0, 0);
    acc[1] = __builtin_amdgcn_mfma_f32_16x16x32_bf16(af, b1, acc[1], 0, 0, 0);
    acc[2] = __builtin_amdgcn_mfma_f32_16x16x32_bf16(af, b2, acc[2], 0, 0, 0);
    acc[3] = __builtin_amdgcn_mfma_f32_16x16x32_bf16(af, b3, acc[3], 0, 0, 0);
  }

  // denominator: quarter-row sum for row lm
  lp += __shfl_xor(lp, 16);
  lp += __shfl_xor(lp, 32);
  if (lq == 0) l_lds[hloc][jq][lm] = lp;

  // jq=1..3 park accumulators in LDS (C layout: row=lq*4+r, col=lm)
  if (jq != 0) {
    #pragma unroll
    for (int nf = 0; nf < 4; ++nf)
      #pragma unroll
      for (int r = 0; r < 4; ++r)
        acc_lds[hloc][jq - 1][lq * 4 + r][nf * 16 + lm] = acc[nf][r];
  }
  __syncthreads();
  if (jq == 0) {
    float linv[4];
    #pragma unroll
    for (int r = 0; r < 4; ++r) {
      int row = lq * 4 + r;
      linv[r] = 1.f / (l_lds[hloc][0][row] + l_lds[hloc][1][row] +
                       l_lds[hloc][2][row] + l_lds[hloc][3][row]);
    }
    #pragma unroll
    for (int nf = 0; nf < 4; ++nf) {
      float bia = bias_att[head * 64 + nf * 16 + lm];
      #pragma unroll
      for (int r = 0; r < 4; ++r) {
        int row = lq * 4 + r;
        float v = acc[nf][r] + acc_lds[hloc][0][row][nf * 16 + lm]
                             + acc_lds[hloc][1][row][nf * 16 + lm]
                             + acc_lds[hloc][2][row][nf * 16 + lm];
        // oS fragment-tile: kp = head*2 + (nf>>1); k%32 = (nf&1)*16 + lm
        size_t idx = (((size_t)(i0 >> 4) * 8) + head * 2 + (nf >> 1)) * 512
                   + row * 32 + (nf & 1) * 16 + lm;
        oS[idx] = f2bf(v * linv[r] + bia);
      }
    }
  }
}

// ---------------- K5: y = oat @ W_out + b_out, then LayerNorm -------------
// Barrier-free K-loop: A-frags from oS fragment tiles (1KB fully-coalesced
// per inst), B-frags direct from L2-hot WoP. One barrier (LN epilogue).
__global__ __launch_bounds__(256, 2)
void k5_gemm_ln(const ushort_t* __restrict__ oS,     // [256][8][16][32]
                const ushort_t* __restrict__ WoP,    // [8][256][32] k-panels
                const float* __restrict__ b_out,
                const float* __restrict__ gamma,
                const float* __restrict__ beta,
                float* __restrict__ out)
{
  __shared__ float y_lds[16][260];
  const int t = threadIdx.x, lane = t & 63, w = t >> 6;
  const int i0 = blockIdx.x * 16;
  const int lq = lane >> 4, lm = lane & 15;

  f32x4 acc[4];
  #pragma unroll
  for (int nf = 0; nf < 4; ++nf) acc[nf] = f32x4{0.f, 0.f, 0.f, 0.f};

  const ushort_t* oS_b = oS + (size_t)(i0 >> 4) * 4096 + lm * 32 + lq * 8;
  const ushort_t* wp0 = WoP + (size_t)(w * 64 +  0 + lm) * 32 + lq * 8;
  const ushort_t* wp1 = WoP + (size_t)(w * 64 + 16 + lm) * 32 + lq * 8;
  const ushort_t* wp2 = WoP + (size_t)(w * 64 + 32 + lm) * 32 + lq * 8;
  const ushort_t* wp3 = WoP + (size_t)(w * 64 + 48 + lm) * 32 + lq * 8;

  #pragma unroll 2
  for (int kp = 0; kp < 8; ++kp) {
    s16x8 a  = *(const s16x8*)(oS_b + (size_t)kp * 512);
    s16x8 b0 = *(const s16x8*)(wp0 + (size_t)kp * 8192);
    s16x8 b1 = *(const s16x8*)(wp1 + (size_t)kp * 8192);
    s16x8 b2 = *(const s16x8*)(wp2 + (size_t)kp * 8192);
    s16x8 b3 = *(const s16x8*)(wp3 + (size_t)kp * 8192);
    acc[0] = __builtin_amdgcn_mfma_f32_16x16x32_bf16(a, b0, acc[0], 0, 0, 0);
    acc[1] = __builtin_amdgcn_mfma_f32_16x16x32_bf16(a, b1, acc[1], 0, 0, 0);
    acc[2] = __builtin_amdgcn_mfma_f32_16x16x32_bf16(a, b2, acc[2], 0, 0, 0);
    acc[3] = __builtin_amdgcn_mfma_f32_16x16x32_bf16(a, b3, acc[3], 0, 0, 0);
  }
  #pragma unroll
  for (int nf = 0; nf < 4; ++nf)
    #pragma unroll
    for (int r = 0; r < 4; ++r) {
      int row = lq * 4 + r;
      int col = w * 64 + nf * 16 + lm;
      y_lds[row][col] = acc[nf][r] + b_out[col];
    }
  __syncthreads();
  f32x4 g  = *(const f32x4*)(gamma + lane * 4);
  f32x4 be = *(const f32x4*)(beta + lane * 4);
  #pragma unroll
  for (int r = w * 4; r < w * 4 + 4; ++r) {
    f32x4 v = *(const f32x4*)&y_lds[r][lane * 4];
    float s1 = v[0] + v[1] + v[2] + v[3];
    float s2 = v[0]*v[0] + v[1]*v[1] + v[2]*v[2] + v[3]*v[3];
    #pragma unroll
    for (int mm = 1; mm < 64; mm <<= 1) { s1 += __shfl_xor(s1, mm); s2 += __shfl_xor(s2, mm); }
    float mu = s1 * (1.f / 256.f);
    float var = s2 * (1.f / 256.f) - mu * mu;
    float rs = rsqrtf(var + 1e-5f);
    f32x4 o;
    #pragma unroll
    for (int u = 0; u < 4; ++u) o[u] = (v[u] - mu) * rs * g[u] + be[u];
    *(f32x4*)(out + (size_t)(i0 + r) * EMB + lane * 4) = o;
  }
}

extern "C" void kernel_launch(void* const* d_in, const int* in_sizes, int n_in,
                              void* d_out, int out_size, void* d_ws, size_t ws_size,
                              hipStream_t stream)
{
  (void)in_sizes; (void)n_in; (void)out_size; (void)ws_size;
  const float* x        = (const float*)d_in[0];
  const int*   adj      = (const int*)d_in[1];
  const float* W_lin    = (const float*)d_in[2];
  const float* att_src  = (const float*)d_in[3];
  const float* att_dst  = (const float*)d_in[4];
  const float* bias_att = (const float*)d_in[5];
  const float* W_out    = (const float*)d_in[6];
  const float* b_out    = (const float*)d_in[7];
  const float* gamma    = (const float*)d_in[8];
  const float* beta     = (const float*)d_in[9];
  float* out = (float*)d_out;

  uint8_t* p = (uint8_t*)d_ws;
  ushort_t* WlP = (ushort_t*)p;  p += (size_t)EMB * EMB * sizeof(ushort_t);
  ushort_t* WoP = (ushort_t*)p;  p += (size_t)EMB * EMB * sizeof(ushort_t);
  ushort_t* hS  = (ushort_t*)p;  p += (size_t)NH * HC * N * sizeof(ushort_t);
  float* a_srcb = (float*)p;     p += (size_t)NH * N * sizeof(float);
  float* a_dstb = (float*)p;     p += (size_t)NH * N * sizeof(float);
  ushort_t* oS  = (ushort_t*)p;  p += (size_t)N * EMB * sizeof(ushort_t);
  unsigned int* abits = (unsigned int*)p; p += (size_t)(N / 32) * N * sizeof(unsigned int);

  k_prep<<<1536, 256, 0, stream>>>(W_lin, WlP, W_out, WoP, adj, abits);
  k1_gemm_h<<<dim3(N / 32, NH), 256, 0, stream>>>(x, WlP, att_src, att_dst, hS, a_srcb, a_dstb);
  k34_attn<<<dim3(N / 16, 2), 512, 0, stream>>>(abits, hS, a_srcb, a_dstb, bias_att, oS);
  k5_gemm_ln<<<N / 16, 256, 0, stream>>>(oS, WoP, b_out, gamma, beta, out);
}

// Round 11
// 176.903 us; speedup vs baseline: 1.1560x; 1.1560x over previous
//
#include <hip/hip_runtime.h>
#include <stdint.h>

#define N    4096
#define EMB  256
#define NH   4
#define HC   64     // channels per head
#define PAD  40     // LDS inner stride (elements): 80B = 20 banks -> <=2-way

typedef __attribute__((ext_vector_type(8))) short s16x8;   // 8 bf16 frag
typedef __attribute__((ext_vector_type(4))) short s16x4;
typedef __attribute__((ext_vector_type(4))) float f32x4;
typedef __attribute__((ext_vector_type(4))) int   i32x4;
typedef unsigned short ushort_t;

__device__ __forceinline__ unsigned short f2bf(float f) {
  unsigned int u = __builtin_bit_cast(unsigned int, f);
  u += 0x7fffu + ((u >> 16) & 1u);      // RNE (finite values only)
  return (unsigned short)(u >> 16);
}

// ---------------- K_prep: fused adj-bitmask + weight-transpose -------------
// blocks 0..4095: one block per adj ROW (R10 lesson: the old wave-per-row
// 64-iteration ballot loop was latency-serial -> 50us @ 800GB/s, hidden
// behind k34 since R6). Thread t loads row[t*16..t*16+15] (4 independent
// i32x4, block reads the 16KB row fully coalesced), builds a 16-bit mask,
// merges pairs via shfl_xor(1), even threads store the 32-bit word.
// blocks 4096..4607: W[k][m] -> k-panel bf16 WP[k/32][m][k%32].
__global__ __launch_bounds__(256)
void k_prep(const float* __restrict__ W0, ushort_t* __restrict__ WP0,
            const float* __restrict__ W1, ushort_t* __restrict__ WP1,
            const int* __restrict__ adj, unsigned int* __restrict__ abits)
{
  int b = blockIdx.x;
  if (b < 4096) {
    const int i = b;
    const int t = threadIdx.x;
    const int* src = adj + (size_t)i * N + t * 16;
    i32x4 v0 = *(const i32x4*)(src);
    i32x4 v1 = *(const i32x4*)(src + 4);
    i32x4 v2 = *(const i32x4*)(src + 8);
    i32x4 v3 = *(const i32x4*)(src + 12);
    unsigned int m = 0;
    #pragma unroll
    for (int u = 0; u < 4; ++u) {
      m |= (v0[u] != 0 ? 1u : 0u) << u;
      m |= (v1[u] != 0 ? 1u : 0u) << (4 + u);
      m |= (v2[u] != 0 ? 1u : 0u) << (8 + u);
      m |= (v3[u] != 0 ? 1u : 0u) << (12 + u);
    }
    if ((i >> 4) == t) m |= 1u << (i & 15);        // self-loop
    unsigned int partner = __shfl_xor(m, 1);
    if ((t & 1) == 0) {
      unsigned int word = m | (partner << 16);
      abits[(size_t)(t >> 1) * N + i] = word;
    }
  } else {
    b -= 4096;
    int k = b & 255;
    int m = threadIdx.x;
    size_t dst = ((size_t)(k >> 5) * 256 + m) * 32 + (k & 31);
    if (b < 256) WP0[dst] = f2bf(W0[k * EMB + m]);
    else         WP1[dst] = f2bf(W1[k * EMB + m]);
  }
}

// ---------------- K1: h = x @ W_lin (bf16 MFMA), barrier-free K-loop -------
__global__ __launch_bounds__(256, 2)
void k1_gemm_h(const float* __restrict__ x,
               const ushort_t* __restrict__ WlP,      // [8][256][32] k-panels
               const float* __restrict__ att_src,     // [4][64]
               const float* __restrict__ att_dst,
               ushort_t* __restrict__ hS,             // [4][128][64][32]
               float* __restrict__ a_srcT,            // [4][4096]
               float* __restrict__ a_dstT)
{
  __shared__ ushort_t T_lds[64][PAD];   // [c][node 0..31]
  __shared__ float red_lds[2][2][32];   // [src/dst][chalf][node]
  const int t = threadIdx.x;
  const int lane = t & 63;
  const int w = t >> 6;
  const int ihalf = w & 1, chalf = w >> 1;
  const int i0 = blockIdx.x * 32;
  const int head = blockIdx.y;
  const int c0 = head * 64;
  const int lq = lane >> 4, lm = lane & 15;

  f32x4 acc[2];
  acc[0] = f32x4{0.f, 0.f, 0.f, 0.f};
  acc[1] = f32x4{0.f, 0.f, 0.f, 0.f};

  const float* xrow = x + (size_t)(i0 + ihalf * 16 + lm) * EMB + lq * 8;
  const ushort_t* wp0 = WlP + (size_t)(c0 + chalf * 32 + lm) * 32 + lq * 8;
  const ushort_t* wp1 = WlP + (size_t)(c0 + chalf * 32 + 16 + lm) * 32 + lq * 8;

  #pragma unroll 2
  for (int kp = 0; kp < 8; ++kp) {
    f32x4 v0 = *(const f32x4*)(xrow + kp * 32);
    f32x4 v1 = *(const f32x4*)(xrow + kp * 32 + 4);
    s16x8 a;
    a[0]=(short)f2bf(v0[0]); a[1]=(short)f2bf(v0[1]); a[2]=(short)f2bf(v0[2]); a[3]=(short)f2bf(v0[3]);
    a[4]=(short)f2bf(v1[0]); a[5]=(short)f2bf(v1[1]); a[6]=(short)f2bf(v1[2]); a[7]=(short)f2bf(v1[3]);
    s16x8 b0 = *(const s16x8*)(wp0 + (size_t)kp * 8192);
    s16x8 b1 = *(const s16x8*)(wp1 + (size_t)kp * 8192);
    acc[0] = __builtin_amdgcn_mfma_f32_16x16x32_bf16(a, b0, acc[0], 0, 0, 0);
    acc[1] = __builtin_amdgcn_mfma_f32_16x16x32_bf16(a, b1, acc[1], 0, 0, 0);
  }

  float ps[4] = {0.f,0.f,0.f,0.f}, pd[4] = {0.f,0.f,0.f,0.f};
  #pragma unroll
  for (int nf = 0; nf < 2; ++nf) {
    int c = chalf * 32 + nf * 16 + lm;
    float wsv = att_src[c0 + c];
    float wdv = att_dst[c0 + c];
    #pragma unroll
    for (int r = 0; r < 4; ++r) {
      float v = acc[nf][r];                 // D: row=lq*4+r, col=lm
      T_lds[c][ihalf * 16 + lq * 4 + r] = f2bf(v);
      ps[r] += v * wsv;
      pd[r] += v * wdv;
    }
  }
  #pragma unroll
  for (int r = 0; r < 4; ++r) {
    #pragma unroll
    for (int mm = 1; mm < 16; mm <<= 1) {
      ps[r] += __shfl_xor(ps[r], mm);
      pd[r] += __shfl_xor(pd[r], mm);
    }
  }
  if (lm == 0) {
    #pragma unroll
    for (int r = 0; r < 4; ++r) {
      int node = ihalf * 16 + lq * 4 + r;
      red_lds[0][chalf][node] = ps[r];
      red_lds[1][chalf][node] = pd[r];
    }
  }
  __syncthreads();
  if (t < 32) {
    a_srcT[head * N + i0 + t] = red_lds[0][0][t] + red_lds[0][1][t];
    a_dstT[head * N + i0 + t] = red_lds[1][0][t] + red_lds[1][1][t];
  }
  {
    int c = t >> 2, seg = t & 3;
    s16x8 v = *(const s16x8*)&T_lds[c][seg * 8];
    size_t base = (((size_t)head * 128 + (i0 >> 5)) * 64 + c) * 32 + seg * 8;
    *(s16x8*)(hS + base) = v;
  }
}

// ---------------- K34: fused masked-softmax attention, atomic-free ---------
// R6-EXACT loop (proven 44us; unroll 2 — R9 lesson: don't touch).
// oS written in fragment-tile layout [i/16][kp][16][32] for k5.
__global__ __launch_bounds__(512, 2)
void k34_attn(const unsigned int* __restrict__ abits, // [128 jw][4096 i]
              const ushort_t* __restrict__ hS,        // [4][128][64][32]
              const float* __restrict__ a_srcT,       // [4][4096]
              const float* __restrict__ a_dstT,       // [4][4096]
              const float* __restrict__ bias_att,     // [256]
              ushort_t* __restrict__ oS)              // [256][8][16][32]
{
  __shared__ float acc_lds[2][3][16][65];  // jq=1..3 partials per local head
  __shared__ float l_lds[2][4][16];

  const int t = threadIdx.x;
  const int lane = t & 63;
  const int w = t >> 6;            // 0..7
  const int hloc = w & 1;          // local head (of the pair)
  const int jq = w >> 1;           // j-quarter 0..3
  const int head = blockIdx.y * 2 + hloc;
  const int i0 = blockIdx.x * 16;
  const int lm = lane & 15, lq = lane >> 4;
  const int ig = i0 + lm;          // this lane's A-row (i)

  const float* asrc_h = a_srcT + head * N;
  const ushort_t* hS_h = hS + (size_t)head * 128 * 64 * 32;
  const float ad = a_dstT[head * N + ig];

  f32x4 acc[4];
  #pragma unroll
  for (int nf = 0; nf < 4; ++nf) acc[nf] = f32x4{0.f, 0.f, 0.f, 0.f};
  float lp = 0.f;

  #pragma unroll 2
  for (int it = 0; it < 32; ++it) {
    const int jw = jq * 32 + it;               // j-window (32 j's)
    const int jl = jw * 32 + lq * 8;           // this lane's first j

    unsigned int word = abits[(size_t)jw * N + ig];      // coalesced 64B
    f32x4 as0 = *(const f32x4*)(asrc_h + jl);
    f32x4 as1 = *(const f32x4*)(asrc_h + jl + 4);

    const ushort_t* tile = hS_h + (size_t)jw * 2048;     // [64 c][32 j]
    s16x8 b0 = *(const s16x8*)(tile + ( 0 + lm) * 32 + lq * 8);
    s16x8 b1 = *(const s16x8*)(tile + (16 + lm) * 32 + lq * 8);
    s16x8 b2 = *(const s16x8*)(tile + (32 + lm) * 32 + lq * 8);
    s16x8 b3 = *(const s16x8*)(tile + (48 + lm) * 32 + lq * 8);

    unsigned int ebits[8];
    #pragma unroll
    for (int jj = 0; jj < 8; ++jj) {
      float asv = (jj < 4) ? as0[jj] : as1[jj - 4];
      float sc = asv + ad;
      sc = fmaxf(sc, 0.2f * sc);                         // leaky relu
      bool con = (word >> (lq * 8 + jj)) & 1u;           // adj + self-loop
      float e = con ? __expf(sc) : 0.f;
      unsigned int eb = __builtin_bit_cast(unsigned int, e) & 0xffff0000u; // trunc bf16
      ebits[jj] = eb;
      lp += __builtin_bit_cast(float, eb);               // sum the SAME rounded value
    }
    i32x4 pk;
    #pragma unroll
    for (int u = 0; u < 4; ++u)
      pk[u] = (int)__builtin_amdgcn_perm(ebits[2 * u + 1], ebits[2 * u], 0x07060302u);
    s16x8 af = __builtin_bit_cast(s16x8, pk);

    acc[0] = __builtin_amdgcn_mfma_f32_16x16x32_bf16(af, b0, acc[0], 0, 0, 0);
    acc[1] = __builtin_amdgcn_mfma_f32_16x16x32_bf16(af, b1, acc[1], 0, 0, 0);
    acc[2] = __builtin_amdgcn_mfma_f32_16x16x32_bf16(af, b2, acc[2], 0, 0, 0);
    acc[3] = __builtin_amdgcn_mfma_f32_16x16x32_bf16(af, b3, acc[3], 0, 0, 0);
  }

  // denominator: quarter-row sum for row lm
  lp += __shfl_xor(lp, 16);
  lp += __shfl_xor(lp, 32);
  if (lq == 0) l_lds[hloc][jq][lm] = lp;

  // jq=1..3 park accumulators in LDS (C layout: row=lq*4+r, col=lm)
  if (jq != 0) {
    #pragma unroll
    for (int nf = 0; nf < 4; ++nf)
      #pragma unroll
      for (int r = 0; r < 4; ++r)
        acc_lds[hloc][jq - 1][lq * 4 + r][nf * 16 + lm] = acc[nf][r];
  }
  __syncthreads();
  if (jq == 0) {
    float linv[4];
    #pragma unroll
    for (int r = 0; r < 4; ++r) {
      int row = lq * 4 + r;
      linv[r] = 1.f / (l_lds[hloc][0][row] + l_lds[hloc][1][row] +
                       l_lds[hloc][2][row] + l_lds[hloc][3][row]);
    }
    #pragma unroll
    for (int nf = 0; nf < 4; ++nf) {
      float bia = bias_att[head * 64 + nf * 16 + lm];
      #pragma unroll
      for (int r = 0; r < 4; ++r) {
        int row = lq * 4 + r;
        float v = acc[nf][r] + acc_lds[hloc][0][row][nf * 16 + lm]
                             + acc_lds[hloc][1][row][nf * 16 + lm]
                             + acc_lds[hloc][2][row][nf * 16 + lm];
        // oS fragment-tile: kp = head*2 + (nf>>1); k%32 = (nf&1)*16 + lm
        size_t idx = (((size_t)(i0 >> 4) * 8) + head * 2 + (nf >> 1)) * 512
                   + row * 32 + (nf & 1) * 16 + lm;
        oS[idx] = f2bf(v * linv[r] + bia);
      }
    }
  }
}

// ---------------- K5: y = oat @ W_out + b_out, then LayerNorm -------------
__global__ __launch_bounds__(256, 2)
void k5_gemm_ln(const ushort_t* __restrict__ oS,     // [256][8][16][32]
                const ushort_t* __restrict__ WoP,    // [8][256][32] k-panels
                const float* __restrict__ b_out,
                const float* __restrict__ gamma,
                const float* __restrict__ beta,
                float* __restrict__ out)
{
  __shared__ float y_lds[16][260];
  const int t = threadIdx.x, lane = t & 63, w = t >> 6;
  const int i0 = blockIdx.x * 16;
  const int lq = lane >> 4, lm = lane & 15;

  f32x4 acc[4];
  #pragma unroll
  for (int nf = 0; nf < 4; ++nf) acc[nf] = f32x4{0.f, 0.f, 0.f, 0.f};

  const ushort_t* oS_b = oS + (size_t)(i0 >> 4) * 4096 + lm * 32 + lq * 8;
  const ushort_t* wp0 = WoP + (size_t)(w * 64 +  0 + lm) * 32 + lq * 8;
  const ushort_t* wp1 = WoP + (size_t)(w * 64 + 16 + lm) * 32 + lq * 8;
  const ushort_t* wp2 = WoP + (size_t)(w * 64 + 32 + lm) * 32 + lq * 8;
  const ushort_t* wp3 = WoP + (size_t)(w * 64 + 48 + lm) * 32 + lq * 8;

  #pragma unroll 2
  for (int kp = 0; kp < 8; ++kp) {
    s16x8 a  = *(const s16x8*)(oS_b + (size_t)kp * 512);
    s16x8 b0 = *(const s16x8*)(wp0 + (size_t)kp * 8192);
    s16x8 b1 = *(const s16x8*)(wp1 + (size_t)kp * 8192);
    s16x8 b2 = *(const s16x8*)(wp2 + (size_t)kp * 8192);
    s16x8 b3 = *(const s16x8*)(wp3 + (size_t)kp * 8192);
    acc[0] = __builtin_amdgcn_mfma_f32_16x16x32_bf16(a, b0, acc[0], 0, 0, 0);
    acc[1] = __builtin_amdgcn_mfma_f32_16x16x32_bf16(a, b1, acc[1], 0, 0, 0);
    acc[2] = __builtin_amdgcn_mfma_f32_16x16x32_bf16(a, b2, acc[2], 0, 0, 0);
    acc[3] = __builtin_amdgcn_mfma_f32_16x16x32_bf16(a, b3, acc[3], 0, 0, 0);
  }
  #pragma unroll
  for (int nf = 0; nf < 4; ++nf)
    #pragma unroll
    for (int r = 0; r < 4; ++r) {
      int row = lq * 4 + r;
      int col = w * 64 + nf * 16 + lm;
      y_lds[row][col] = acc[nf][r] + b_out[col];
    }
  __syncthreads();
  f32x4 g  = *(const f32x4*)(gamma + lane * 4);
  f32x4 be = *(const f32x4*)(beta + lane * 4);
  #pragma unroll
  for (int r = w * 4; r < w * 4 + 4; ++r) {
    f32x4 v = *(const f32x4*)&y_lds[r][lane * 4];
    float s1 = v[0] + v[1] + v[2] + v[3];
    float s2 = v[0]*v[0] + v[1]*v[1] + v[2]*v[2] + v[3]*v[3];
    #pragma unroll
    for (int mm = 1; mm < 64; mm <<= 1) { s1 += __shfl_xor(s1, mm); s2 += __shfl_xor(s2, mm); }
    float mu = s1 * (1.f / 256.f);
    float var = s2 * (1.f / 256.f) - mu * mu;
    float rs = rsqrtf(var + 1e-5f);
    f32x4 o;
    #pragma unroll
    for (int u = 0; u < 4; ++u) o[u] = (v[u] - mu) * rs * g[u] + be[u];
    *(f32x4*)(out + (size_t)(i0 + r) * EMB + lane * 4) = o;
  }
}

extern "C" void kernel_launch(void* const* d_in, const int* in_sizes, int n_in,
                              void* d_out, int out_size, void* d_ws, size_t ws_size,
                              hipStream_t stream)
{
  (void)in_sizes; (void)n_in; (void)out_size; (void)ws_size;
  const float* x        = (const float*)d_in[0];
  const int*   adj      = (const int*)d_in[1];
  const float* W_lin    = (const float*)d_in[2];
  const float* att_src  = (const float*)d_in[3];
  const float* att_dst  = (const float*)d_in[4];
  const float* bias_att = (const float*)d_in[5];
  const float* W_out    = (const float*)d_in[6];
  const float* b_out    = (const float*)d_in[7];
  const float* gamma    = (const float*)d_in[8];
  const float* beta     = (const float*)d_in[9];
  float* out = (float*)d_out;

  uint8_t* p = (uint8_t*)d_ws;
  ushort_t* WlP = (ushort_t*)p;  p += (size_t)EMB * EMB * sizeof(ushort_t);
  ushort_t* WoP = (ushort_t*)p;  p += (size_t)EMB * EMB * sizeof(ushort_t);
  ushort_t* hS  = (ushort_t*)p;  p += (size_t)NH * HC * N * sizeof(ushort_t);
  float* a_srcb = (float*)p;     p += (size_t)NH * N * sizeof(float);
  float* a_dstb = (float*)p;     p += (size_t)NH * N * sizeof(float);
  ushort_t* oS  = (ushort_t*)p;  p += (size_t)N * EMB * sizeof(ushort_t);
  unsigned int* abits = (unsigned int*)p; p += (size_t)(N / 32) * N * sizeof(unsigned int);

  k_prep<<<4096 + 512, 256, 0, stream>>>(W_lin, WlP, W_out, WoP, adj, abits);
  k1_gemm_h<<<dim3(N / 32, NH), 256, 0, stream>>>(x, WlP, att_src, att_dst, hS, a_srcb, a_dstb);
  k34_attn<<<dim3(N / 16, 2), 512, 0, stream>>>(abits, hS, a_srcb, a_dstb, bias_att, oS);
  k5_gemm_ln<<<N / 16, 256, 0, stream>>>(oS, WoP, b_out, gamma, beta, out);
}

// Round 12
// 167.233 us; speedup vs baseline: 1.2229x; 1.0578x over previous
//
#include <hip/hip_runtime.h>
#include <stdint.h>

#define N    4096
#define EMB  256
#define NH   4
#define HC   64     // channels per head
#define PAD  40     // LDS inner stride (elements): 80B = 20 banks -> <=2-way

typedef __attribute__((ext_vector_type(8))) short s16x8;   // 8 bf16 frag
typedef __attribute__((ext_vector_type(4))) short s16x4;
typedef __attribute__((ext_vector_type(4))) float f32x4;
typedef __attribute__((ext_vector_type(4))) int   i32x4;
typedef unsigned short ushort_t;

__device__ __forceinline__ unsigned short f2bf(float f) {
  unsigned int u = __builtin_bit_cast(unsigned int, f);
  u += 0x7fffu + ((u >> 16) & 1u);      // RNE (finite values only)
  return (unsigned short)(u >> 16);
}

// ---------------- K_prep: fused adj-bitmask + weight-transpose -------------
// (R11-proven: one block per adj row, coalesced 16KB row read, shfl merge.)
__global__ __launch_bounds__(256)
void k_prep(const float* __restrict__ W0, ushort_t* __restrict__ WP0,
            const float* __restrict__ W1, ushort_t* __restrict__ WP1,
            const int* __restrict__ adj, unsigned int* __restrict__ abits)
{
  int b = blockIdx.x;
  if (b < 4096) {
    const int i = b;
    const int t = threadIdx.x;
    const int* src = adj + (size_t)i * N + t * 16;
    i32x4 v0 = *(const i32x4*)(src);
    i32x4 v1 = *(const i32x4*)(src + 4);
    i32x4 v2 = *(const i32x4*)(src + 8);
    i32x4 v3 = *(const i32x4*)(src + 12);
    unsigned int m = 0;
    #pragma unroll
    for (int u = 0; u < 4; ++u) {
      m |= (v0[u] != 0 ? 1u : 0u) << u;
      m |= (v1[u] != 0 ? 1u : 0u) << (4 + u);
      m |= (v2[u] != 0 ? 1u : 0u) << (8 + u);
      m |= (v3[u] != 0 ? 1u : 0u) << (12 + u);
    }
    if ((i >> 4) == t) m |= 1u << (i & 15);        // self-loop
    unsigned int partner = __shfl_xor(m, 1);
    if ((t & 1) == 0) {
      unsigned int word = m | (partner << 16);
      abits[(size_t)(t >> 1) * N + i] = word;
    }
  } else {
    b -= 4096;
    int k = b & 255;
    int m = threadIdx.x;
    size_t dst = ((size_t)(k >> 5) * 256 + m) * 32 + (k & 31);
    if (b < 256) WP0[dst] = f2bf(W0[k * EMB + m]);
    else         WP1[dst] = f2bf(W1[k * EMB + m]);
  }
}

// ---------------- K1: h = x @ W_lin (bf16 MFMA), barrier-free K-loop -------
__global__ __launch_bounds__(256, 2)
void k1_gemm_h(const float* __restrict__ x,
               const ushort_t* __restrict__ WlP,      // [8][256][32] k-panels
               const float* __restrict__ att_src,     // [4][64]
               const float* __restrict__ att_dst,
               ushort_t* __restrict__ hS,             // [4][128][64][32]
               float* __restrict__ a_srcT,            // [4][4096]
               float* __restrict__ a_dstT)
{
  __shared__ ushort_t T_lds[64][PAD];   // [c][node 0..31]
  __shared__ float red_lds[2][2][32];   // [src/dst][chalf][node]
  const int t = threadIdx.x;
  const int lane = t & 63;
  const int w = t >> 6;
  const int ihalf = w & 1, chalf = w >> 1;
  const int i0 = blockIdx.x * 32;
  const int head = blockIdx.y;
  const int c0 = head * 64;
  const int lq = lane >> 4, lm = lane & 15;

  f32x4 acc[2];
  acc[0] = f32x4{0.f, 0.f, 0.f, 0.f};
  acc[1] = f32x4{0.f, 0.f, 0.f, 0.f};

  const float* xrow = x + (size_t)(i0 + ihalf * 16 + lm) * EMB + lq * 8;
  const ushort_t* wp0 = WlP + (size_t)(c0 + chalf * 32 + lm) * 32 + lq * 8;
  const ushort_t* wp1 = WlP + (size_t)(c0 + chalf * 32 + 16 + lm) * 32 + lq * 8;

  #pragma unroll 2
  for (int kp = 0; kp < 8; ++kp) {
    f32x4 v0 = *(const f32x4*)(xrow + kp * 32);
    f32x4 v1 = *(const f32x4*)(xrow + kp * 32 + 4);
    s16x8 a;
    a[0]=(short)f2bf(v0[0]); a[1]=(short)f2bf(v0[1]); a[2]=(short)f2bf(v0[2]); a[3]=(short)f2bf(v0[3]);
    a[4]=(short)f2bf(v1[0]); a[5]=(short)f2bf(v1[1]); a[6]=(short)f2bf(v1[2]); a[7]=(short)f2bf(v1[3]);
    s16x8 b0 = *(const s16x8*)(wp0 + (size_t)kp * 8192);
    s16x8 b1 = *(const s16x8*)(wp1 + (size_t)kp * 8192);
    acc[0] = __builtin_amdgcn_mfma_f32_16x16x32_bf16(a, b0, acc[0], 0, 0, 0);
    acc[1] = __builtin_amdgcn_mfma_f32_16x16x32_bf16(a, b1, acc[1], 0, 0, 0);
  }

  float ps[4] = {0.f,0.f,0.f,0.f}, pd[4] = {0.f,0.f,0.f,0.f};
  #pragma unroll
  for (int nf = 0; nf < 2; ++nf) {
    int c = chalf * 32 + nf * 16 + lm;
    float wsv = att_src[c0 + c];
    float wdv = att_dst[c0 + c];
    #pragma unroll
    for (int r = 0; r < 4; ++r) {
      float v = acc[nf][r];                 // D: row=lq*4+r, col=lm
      T_lds[c][ihalf * 16 + lq * 4 + r] = f2bf(v);
      ps[r] += v * wsv;
      pd[r] += v * wdv;
    }
  }
  #pragma unroll
  for (int r = 0; r < 4; ++r) {
    #pragma unroll
    for (int mm = 1; mm < 16; mm <<= 1) {
      ps[r] += __shfl_xor(ps[r], mm);
      pd[r] += __shfl_xor(pd[r], mm);
    }
  }
  if (lm == 0) {
    #pragma unroll
    for (int r = 0; r < 4; ++r) {
      int node = ihalf * 16 + lq * 4 + r;
      red_lds[0][chalf][node] = ps[r];
      red_lds[1][chalf][node] = pd[r];
    }
  }
  __syncthreads();
  if (t < 32) {
    a_srcT[head * N + i0 + t] = red_lds[0][0][t] + red_lds[0][1][t];
    a_dstT[head * N + i0 + t] = red_lds[1][0][t] + red_lds[1][1][t];
  }
  {
    int c = t >> 2, seg = t & 3;
    s16x8 v = *(const s16x8*)&T_lds[c][seg * 8];
    size_t base = (((size_t)head * 128 + (i0 >> 5)) * 64 + c) * 32 + seg * 8;
    *(s16x8*)(hS + base) = v;
  }
}

// ---------------- K34: fused masked-softmax attention, atomic-free ---------
// R12: per-wave i-tile 16 -> 32 (two A-frag row-sets share ONE B-frag set).
// Rationale: B-frags + a_src depend only on j; at i-tile 16 the kernel moved
// ~770MB through L2 (17 TB/s, 50% of ceiling) — doubling i per wave halves
// L2 traffic AND doubles per-wave ILP (8 MFMAs + 2 e-chains in flight).
// Block 512 thr = 8 waves (2 heads x 4 jq), grid (N/32, 2) = 256 blocks
// (1/CU, 8 waves/CU — R6-R8 showed TLP beyond ~12 waves/CU unused).
// launch_bounds(512,1): VGPR cap 256, no spill (R3 hazard). oS layout as R11.
__global__ __launch_bounds__(512, 1)
void k34_attn(const unsigned int* __restrict__ abits, // [128 jw][4096 i]
              const ushort_t* __restrict__ hS,        // [4][128][64][32]
              const float* __restrict__ a_srcT,       // [4][4096]
              const float* __restrict__ a_dstT,       // [4][4096]
              const float* __restrict__ bias_att,     // [256]
              ushort_t* __restrict__ oS)              // [256][8][16][32]
{
  __shared__ float acc_lds[2][3][32][65];  // jq=1..3 partials per local head
  __shared__ float l_lds[2][4][32];

  const int t = threadIdx.x;
  const int lane = t & 63;
  const int w = t >> 6;            // 0..7
  const int hloc = w & 1;          // local head (of the pair)
  const int jq = w >> 1;           // j-quarter 0..3
  const int head = blockIdx.y * 2 + hloc;
  const int i0 = blockIdx.x * 32;
  const int lm = lane & 15, lq = lane >> 4;
  const int ig0 = i0 + lm;         // A-row, i-subtile 0
  const int ig1 = i0 + 16 + lm;    // A-row, i-subtile 1

  const float* asrc_h = a_srcT + head * N;
  const ushort_t* hS_h = hS + (size_t)head * 128 * 64 * 32;
  const float ad0 = a_dstT[head * N + ig0];
  const float ad1 = a_dstT[head * N + ig1];

  f32x4 acc[2][4];
  #pragma unroll
  for (int s = 0; s < 2; ++s)
    #pragma unroll
    for (int nf = 0; nf < 4; ++nf) acc[s][nf] = f32x4{0.f, 0.f, 0.f, 0.f};
  float lp0 = 0.f, lp1 = 0.f;

  #pragma unroll 2
  for (int it = 0; it < 32; ++it) {
    const int jw = jq * 32 + it;               // j-window (32 j's)
    const int jl = jw * 32 + lq * 8;           // this lane's first j

    unsigned int word0 = abits[(size_t)jw * N + ig0];
    unsigned int word1 = abits[(size_t)jw * N + ig1];
    f32x4 as0 = *(const f32x4*)(asrc_h + jl);
    f32x4 as1 = *(const f32x4*)(asrc_h + jl + 4);

    const ushort_t* tile = hS_h + (size_t)jw * 2048;     // [64 c][32 j]
    s16x8 b0 = *(const s16x8*)(tile + ( 0 + lm) * 32 + lq * 8);
    s16x8 b1 = *(const s16x8*)(tile + (16 + lm) * 32 + lq * 8);
    s16x8 b2 = *(const s16x8*)(tile + (32 + lm) * 32 + lq * 8);
    s16x8 b3 = *(const s16x8*)(tile + (48 + lm) * 32 + lq * 8);

    unsigned int e0[8], e1[8];
    #pragma unroll
    for (int jj = 0; jj < 8; ++jj) {
      float asv = (jj < 4) ? as0[jj] : as1[jj - 4];
      float sc0 = asv + ad0;
      float sc1 = asv + ad1;
      sc0 = fmaxf(sc0, 0.2f * sc0);                      // leaky relu
      sc1 = fmaxf(sc1, 0.2f * sc1);
      bool c0 = (word0 >> (lq * 8 + jj)) & 1u;           // adj + self-loop
      bool c1 = (word1 >> (lq * 8 + jj)) & 1u;
      float v0 = c0 ? __expf(sc0) : 0.f;
      float v1 = c1 ? __expf(sc1) : 0.f;
      unsigned int eb0 = __builtin_bit_cast(unsigned int, v0) & 0xffff0000u;
      unsigned int eb1 = __builtin_bit_cast(unsigned int, v1) & 0xffff0000u;
      e0[jj] = eb0;
      e1[jj] = eb1;
      lp0 += __builtin_bit_cast(float, eb0);             // sum the SAME rounded value
      lp1 += __builtin_bit_cast(float, eb1);
    }
    i32x4 p0, p1;
    #pragma unroll
    for (int u = 0; u < 4; ++u) {
      p0[u] = (int)__builtin_amdgcn_perm(e0[2 * u + 1], e0[2 * u], 0x07060302u);
      p1[u] = (int)__builtin_amdgcn_perm(e1[2 * u + 1], e1[2 * u], 0x07060302u);
    }
    s16x8 af0 = __builtin_bit_cast(s16x8, p0);
    s16x8 af1 = __builtin_bit_cast(s16x8, p1);

    acc[0][0] = __builtin_amdgcn_mfma_f32_16x16x32_bf16(af0, b0, acc[0][0], 0, 0, 0);
    acc[0][1] = __builtin_amdgcn_mfma_f32_16x16x32_bf16(af0, b1, acc[0][1], 0, 0, 0);
    acc[0][2] = __builtin_amdgcn_mfma_f32_16x16x32_bf16(af0, b2, acc[0][2], 0, 0, 0);
    acc[0][3] = __builtin_amdgcn_mfma_f32_16x16x32_bf16(af0, b3, acc[0][3], 0, 0, 0);
    acc[1][0] = __builtin_amdgcn_mfma_f32_16x16x32_bf16(af1, b0, acc[1][0], 0, 0, 0);
    acc[1][1] = __builtin_amdgcn_mfma_f32_16x16x32_bf16(af1, b1, acc[1][1], 0, 0, 0);
    acc[1][2] = __builtin_amdgcn_mfma_f32_16x16x32_bf16(af1, b2, acc[1][2], 0, 0, 0);
    acc[1][3] = __builtin_amdgcn_mfma_f32_16x16x32_bf16(af1, b3, acc[1][3], 0, 0, 0);
  }

  // denominators: quarter-row sums for rows lm (sub 0) and 16+lm (sub 1)
  lp0 += __shfl_xor(lp0, 16);
  lp0 += __shfl_xor(lp0, 32);
  lp1 += __shfl_xor(lp1, 16);
  lp1 += __shfl_xor(lp1, 32);
  if (lq == 0) {
    l_lds[hloc][jq][lm] = lp0;
    l_lds[hloc][jq][16 + lm] = lp1;
  }

  // jq=1..3 park accumulators in LDS (C layout: row=isub*16+lq*4+r, col=lm)
  if (jq != 0) {
    #pragma unroll
    for (int s = 0; s < 2; ++s)
      #pragma unroll
      for (int nf = 0; nf < 4; ++nf)
        #pragma unroll
        for (int r = 0; r < 4; ++r)
          acc_lds[hloc][jq - 1][s * 16 + lq * 4 + r][nf * 16 + lm] = acc[s][nf][r];
  }
  __syncthreads();
  if (jq == 0) {
    #pragma unroll
    for (int s = 0; s < 2; ++s) {
      float linv[4];
      #pragma unroll
      for (int r = 0; r < 4; ++r) {
        int row = s * 16 + lq * 4 + r;
        linv[r] = 1.f / (l_lds[hloc][0][row] + l_lds[hloc][1][row] +
                         l_lds[hloc][2][row] + l_lds[hloc][3][row]);
      }
      #pragma unroll
      for (int nf = 0; nf < 4; ++nf) {
        float bia = bias_att[head * 64 + nf * 16 + lm];
        #pragma unroll
        for (int r = 0; r < 4; ++r) {
          int row = s * 16 + lq * 4 + r;
          float v = acc[s][nf][r] + acc_lds[hloc][0][row][nf * 16 + lm]
                                  + acc_lds[hloc][1][row][nf * 16 + lm]
                                  + acc_lds[hloc][2][row][nf * 16 + lm];
          // oS fragment-tile: kp = head*2 + (nf>>1); k%32 = (nf&1)*16 + lm
          size_t idx = (((size_t)((i0 >> 4) + s) * 8) + head * 2 + (nf >> 1)) * 512
                     + (lq * 4 + r) * 32 + (nf & 1) * 16 + lm;
          oS[idx] = f2bf(v * linv[r] + bia);
        }
      }
    }
  }
}

// ---------------- K5: y = oat @ W_out + b_out, then LayerNorm -------------
__global__ __launch_bounds__(256, 2)
void k5_gemm_ln(const ushort_t* __restrict__ oS,     // [256][8][16][32]
                const ushort_t* __restrict__ WoP,    // [8][256][32] k-panels
                const float* __restrict__ b_out,
                const float* __restrict__ gamma,
                const float* __restrict__ beta,
                float* __restrict__ out)
{
  __shared__ float y_lds[16][260];
  const int t = threadIdx.x, lane = t & 63, w = t >> 6;
  const int i0 = blockIdx.x * 16;
  const int lq = lane >> 4, lm = lane & 15;

  f32x4 acc[4];
  #pragma unroll
  for (int nf = 0; nf < 4; ++nf) acc[nf] = f32x4{0.f, 0.f, 0.f, 0.f};

  const ushort_t* oS_b = oS + (size_t)(i0 >> 4) * 4096 + lm * 32 + lq * 8;
  const ushort_t* wp0 = WoP + (size_t)(w * 64 +  0 + lm) * 32 + lq * 8;
  const ushort_t* wp1 = WoP + (size_t)(w * 64 + 16 + lm) * 32 + lq * 8;
  const ushort_t* wp2 = WoP + (size_t)(w * 64 + 32 + lm) * 32 + lq * 8;
  const ushort_t* wp3 = WoP + (size_t)(w * 64 + 48 + lm) * 32 + lq * 8;

  #pragma unroll 2
  for (int kp = 0; kp < 8; ++kp) {
    s16x8 a  = *(const s16x8*)(oS_b + (size_t)kp * 512);
    s16x8 b0 = *(const s16x8*)(wp0 + (size_t)kp * 8192);
    s16x8 b1 = *(const s16x8*)(wp1 + (size_t)kp * 8192);
    s16x8 b2 = *(const s16x8*)(wp2 + (size_t)kp * 8192);
    s16x8 b3 = *(const s16x8*)(wp3 + (size_t)kp * 8192);
    acc[0] = __builtin_amdgcn_mfma_f32_16x16x32_bf16(a, b0, acc[0], 0, 0, 0);
    acc[1] = __builtin_amdgcn_mfma_f32_16x16x32_bf16(a, b1, acc[1], 0, 0, 0);
    acc[2] = __builtin_amdgcn_mfma_f32_16x16x32_bf16(a, b2, acc[2], 0, 0, 0);
    acc[3] = __builtin_amdgcn_mfma_f32_16x16x32_bf16(a, b3, acc[3], 0, 0, 0);
  }
  #pragma unroll
  for (int nf = 0; nf < 4; ++nf)
    #pragma unroll
    for (int r = 0; r < 4; ++r) {
      int row = lq * 4 + r;
      int col = w * 64 + nf * 16 + lm;
      y_lds[row][col] = acc[nf][r] + b_out[col];
    }
  __syncthreads();
  f32x4 g  = *(const f32x4*)(gamma + lane * 4);
  f32x4 be = *(const f32x4*)(beta + lane * 4);
  #pragma unroll
  for (int r = w * 4; r < w * 4 + 4; ++r) {
    f32x4 v = *(const f32x4*)&y_lds[r][lane * 4];
    float s1 = v[0] + v[1] + v[2] + v[3];
    float s2 = v[0]*v[0] + v[1]*v[1] + v[2]*v[2] + v[3]*v[3];
    #pragma unroll
    for (int mm = 1; mm < 64; mm <<= 1) { s1 += __shfl_xor(s1, mm); s2 += __shfl_xor(s2, mm); }
    float mu = s1 * (1.f / 256.f);
    float var = s2 * (1.f / 256.f) - mu * mu;
    float rs = rsqrtf(var + 1e-5f);
    f32x4 o;
    #pragma unroll
    for (int u = 0; u < 4; ++u) o[u] = (v[u] - mu) * rs * g[u] + be[u];
    *(f32x4*)(out + (size_t)(i0 + r) * EMB + lane * 4) = o;
  }
}

extern "C" void kernel_launch(void* const* d_in, const int* in_sizes, int n_in,
                              void* d_out, int out_size, void* d_ws, size_t ws_size,
                              hipStream_t stream)
{
  (void)in_sizes; (void)n_in; (void)out_size; (void)ws_size;
  const float* x        = (const float*)d_in[0];
  const int*   adj      = (const int*)d_in[1];
  const float* W_lin    = (const float*)d_in[2];
  const float* att_src  = (const float*)d_in[3];
  const float* att_dst  = (const float*)d_in[4];
  const float* bias_att = (const float*)d_in[5];
  const float* W_out    = (const float*)d_in[6];
  const float* b_out    = (const float*)d_in[7];
  const float* gamma    = (const float*)d_in[8];
  const float* beta     = (const float*)d_in[9];
  float* out = (float*)d_out;

  uint8_t* p = (uint8_t*)d_ws;
  ushort_t* WlP = (ushort_t*)p;  p += (size_t)EMB * EMB * sizeof(ushort_t);
  ushort_t* WoP = (ushort_t*)p;  p += (size_t)EMB * EMB * sizeof(ushort_t);
  ushort_t* hS  = (ushort_t*)p;  p += (size_t)NH * HC * N * sizeof(ushort_t);
  float* a_srcb = (float*)p;     p += (size_t)NH * N * sizeof(float);
  float* a_dstb = (float*)p;     p += (size_t)NH * N * sizeof(float);
  ushort_t* oS  = (ushort_t*)p;  p += (size_t)N * EMB * sizeof(ushort_t);
  unsigned int* abits = (unsigned int*)p; p += (size_t)(N / 32) * N * sizeof(unsigned int);

  k_prep<<<4096 + 512, 256, 0, stream>>>(W_lin, WlP, W_out, WoP, adj, abits);
  k1_gemm_h<<<dim3(N / 32, NH), 256, 0, stream>>>(x, WlP, att_src, att_dst, hS, a_srcb, a_dstb);
  k34_attn<<<dim3(N / 32, 2), 512, 0, stream>>>(abits, hS, a_srcb, a_dstb, bias_att, oS);
  k5_gemm_ln<<<N / 16, 256, 0, stream>>>(oS, WoP, b_out, gamma, beta, out);
}

// Round 13
// 165.620 us; speedup vs baseline: 1.2348x; 1.0097x over previous
//
#include <hip/hip_runtime.h>
#include <stdint.h>

#define N    4096
#define EMB  256
#define NH   4
#define HC   64     // channels per head
#define PAD  40     // LDS inner stride (elements): 80B = 20 banks -> <=2-way

typedef __attribute__((ext_vector_type(8))) short s16x8;   // 8 bf16 frag
typedef __attribute__((ext_vector_type(4))) short s16x4;
typedef __attribute__((ext_vector_type(4))) float f32x4;
typedef __attribute__((ext_vector_type(4))) int   i32x4;
typedef unsigned short ushort_t;

__device__ __forceinline__ unsigned short f2bf(float f) {
  unsigned int u = __builtin_bit_cast(unsigned int, f);
  u += 0x7fffu + ((u >> 16) & 1u);      // RNE (finite values only)
  return (unsigned short)(u >> 16);
}

// ---------------- K_prep: fused adj-bitmask + weight-transpose -------------
// (R11-proven: one block per adj row, coalesced 16KB row read, shfl merge.)
__global__ __launch_bounds__(256)
void k_prep(const float* __restrict__ W0, ushort_t* __restrict__ WP0,
            const float* __restrict__ W1, ushort_t* __restrict__ WP1,
            const int* __restrict__ adj, unsigned int* __restrict__ abits)
{
  int b = blockIdx.x;
  if (b < 4096) {
    const int i = b;
    const int t = threadIdx.x;
    const int* src = adj + (size_t)i * N + t * 16;
    i32x4 v0 = *(const i32x4*)(src);
    i32x4 v1 = *(const i32x4*)(src + 4);
    i32x4 v2 = *(const i32x4*)(src + 8);
    i32x4 v3 = *(const i32x4*)(src + 12);
    unsigned int m = 0;
    #pragma unroll
    for (int u = 0; u < 4; ++u) {
      m |= (v0[u] != 0 ? 1u : 0u) << u;
      m |= (v1[u] != 0 ? 1u : 0u) << (4 + u);
      m |= (v2[u] != 0 ? 1u : 0u) << (8 + u);
      m |= (v3[u] != 0 ? 1u : 0u) << (12 + u);
    }
    if ((i >> 4) == t) m |= 1u << (i & 15);        // self-loop
    unsigned int partner = __shfl_xor(m, 1);
    if ((t & 1) == 0) {
      unsigned int word = m | (partner << 16);
      abits[(size_t)(t >> 1) * N + i] = word;
    }
  } else {
    b -= 4096;
    int k = b & 255;
    int m = threadIdx.x;
    size_t dst = ((size_t)(k >> 5) * 256 + m) * 32 + (k & 31);
    if (b < 256) WP0[dst] = f2bf(W0[k * EMB + m]);
    else         WP1[dst] = f2bf(W1[k * EMB + m]);
  }
}

// ---------------- K1: h = x @ W_lin (bf16 MFMA), barrier-free K-loop -------
__global__ __launch_bounds__(256, 2)
void k1_gemm_h(const float* __restrict__ x,
               const ushort_t* __restrict__ WlP,      // [8][256][32] k-panels
               const float* __restrict__ att_src,     // [4][64]
               const float* __restrict__ att_dst,
               ushort_t* __restrict__ hS,             // [4][128][64][32]
               float* __restrict__ a_srcT,            // [4][4096]
               float* __restrict__ a_dstT)
{
  __shared__ ushort_t T_lds[64][PAD];   // [c][node 0..31]
  __shared__ float red_lds[2][2][32];   // [src/dst][chalf][node]
  const int t = threadIdx.x;
  const int lane = t & 63;
  const int w = t >> 6;
  const int ihalf = w & 1, chalf = w >> 1;
  const int i0 = blockIdx.x * 32;
  const int head = blockIdx.y;
  const int c0 = head * 64;
  const int lq = lane >> 4, lm = lane & 15;

  f32x4 acc[2];
  acc[0] = f32x4{0.f, 0.f, 0.f, 0.f};
  acc[1] = f32x4{0.f, 0.f, 0.f, 0.f};

  const float* xrow = x + (size_t)(i0 + ihalf * 16 + lm) * EMB + lq * 8;
  const ushort_t* wp0 = WlP + (size_t)(c0 + chalf * 32 + lm) * 32 + lq * 8;
  const ushort_t* wp1 = WlP + (size_t)(c0 + chalf * 32 + 16 + lm) * 32 + lq * 8;

  #pragma unroll 2
  for (int kp = 0; kp < 8; ++kp) {
    f32x4 v0 = *(const f32x4*)(xrow + kp * 32);
    f32x4 v1 = *(const f32x4*)(xrow + kp * 32 + 4);
    s16x8 a;
    a[0]=(short)f2bf(v0[0]); a[1]=(short)f2bf(v0[1]); a[2]=(short)f2bf(v0[2]); a[3]=(short)f2bf(v0[3]);
    a[4]=(short)f2bf(v1[0]); a[5]=(short)f2bf(v1[1]); a[6]=(short)f2bf(v1[2]); a[7]=(short)f2bf(v1[3]);
    s16x8 b0 = *(const s16x8*)(wp0 + (size_t)kp * 8192);
    s16x8 b1 = *(const s16x8*)(wp1 + (size_t)kp * 8192);
    acc[0] = __builtin_amdgcn_mfma_f32_16x16x32_bf16(a, b0, acc[0], 0, 0, 0);
    acc[1] = __builtin_amdgcn_mfma_f32_16x16x32_bf16(a, b1, acc[1], 0, 0, 0);
  }

  float ps[4] = {0.f,0.f,0.f,0.f}, pd[4] = {0.f,0.f,0.f,0.f};
  #pragma unroll
  for (int nf = 0; nf < 2; ++nf) {
    int c = chalf * 32 + nf * 16 + lm;
    float wsv = att_src[c0 + c];
    float wdv = att_dst[c0 + c];
    #pragma unroll
    for (int r = 0; r < 4; ++r) {
      float v = acc[nf][r];                 // D: row=lq*4+r, col=lm
      T_lds[c][ihalf * 16 + lq * 4 + r] = f2bf(v);
      ps[r] += v * wsv;
      pd[r] += v * wdv;
    }
  }
  #pragma unroll
  for (int r = 0; r < 4; ++r) {
    #pragma unroll
    for (int mm = 1; mm < 16; mm <<= 1) {
      ps[r] += __shfl_xor(ps[r], mm);
      pd[r] += __shfl_xor(pd[r], mm);
    }
  }
  if (lm == 0) {
    #pragma unroll
    for (int r = 0; r < 4; ++r) {
      int node = ihalf * 16 + lq * 4 + r;
      red_lds[0][chalf][node] = ps[r];
      red_lds[1][chalf][node] = pd[r];
    }
  }
  __syncthreads();
  if (t < 32) {
    a_srcT[head * N + i0 + t] = red_lds[0][0][t] + red_lds[0][1][t];
    a_dstT[head * N + i0 + t] = red_lds[1][0][t] + red_lds[1][1][t];
  }
  {
    int c = t >> 2, seg = t & 3;
    s16x8 v = *(const s16x8*)&T_lds[c][seg * 8];
    size_t base = (((size_t)head * 128 + (i0 >> 5)) * 64 + c) * 32 + seg * 8;
    *(s16x8*)(hS + base) = v;
  }
}

// ---------------- K34: fused masked-softmax attention, atomic-free ---------
// R13: R12's proven i-tile-32 ILP body, reshaped to 1 head/block x 8
// j-eighths (16 iters/wave), grid (N/32, NH) = 512 blocks -> 2 blocks/CU,
// 16 waves/CU (R12 was 1 block/CU: no co-resident work to hide the epilogue
// tail). Per-iter body byte-identical to R12: 2 abits + 2 e-chains + 4
// shared B-frags + 8 MFMAs. L2 B-traffic unchanged (reuse is within-wave).
// (512,2): VGPR cap 128 so both blocks fit. Failure signature = VGPR<=64.
__global__ __launch_bounds__(512, 2)
void k34_attn(const unsigned int* __restrict__ abits, // [128 jw][4096 i]
              const ushort_t* __restrict__ hS,        // [4][128][64][32]
              const float* __restrict__ a_srcT,       // [4][4096]
              const float* __restrict__ a_dstT,       // [4][4096]
              const float* __restrict__ bias_att,     // [256]
              ushort_t* __restrict__ oS)              // [256][8][16][32]
{
  __shared__ float acc_lds[7][32][65];     // jq=1..7 partials
  __shared__ float l_lds[8][32];

  const int t = threadIdx.x;
  const int lane = t & 63;
  const int jq = t >> 6;           // 0..7 = j-eighth
  const int head = blockIdx.y;
  const int i0 = blockIdx.x * 32;
  const int lm = lane & 15, lq = lane >> 4;
  const int ig0 = i0 + lm;         // A-row, i-subtile 0
  const int ig1 = i0 + 16 + lm;    // A-row, i-subtile 1

  const float* asrc_h = a_srcT + head * N;
  const ushort_t* hS_h = hS + (size_t)head * 128 * 64 * 32;
  const float ad0 = a_dstT[head * N + ig0];
  const float ad1 = a_dstT[head * N + ig1];

  f32x4 acc[2][4];
  #pragma unroll
  for (int s = 0; s < 2; ++s)
    #pragma unroll
    for (int nf = 0; nf < 4; ++nf) acc[s][nf] = f32x4{0.f, 0.f, 0.f, 0.f};
  float lp0 = 0.f, lp1 = 0.f;

  #pragma unroll 2
  for (int it = 0; it < 16; ++it) {
    const int jw = jq * 16 + it;               // j-window (32 j's)
    const int jl = jw * 32 + lq * 8;           // this lane's first j

    unsigned int word0 = abits[(size_t)jw * N + ig0];
    unsigned int word1 = abits[(size_t)jw * N + ig1];
    f32x4 as0 = *(const f32x4*)(asrc_h + jl);
    f32x4 as1 = *(const f32x4*)(asrc_h + jl + 4);

    const ushort_t* tile = hS_h + (size_t)jw * 2048;     // [64 c][32 j]
    s16x8 b0 = *(const s16x8*)(tile + ( 0 + lm) * 32 + lq * 8);
    s16x8 b1 = *(const s16x8*)(tile + (16 + lm) * 32 + lq * 8);
    s16x8 b2 = *(const s16x8*)(tile + (32 + lm) * 32 + lq * 8);
    s16x8 b3 = *(const s16x8*)(tile + (48 + lm) * 32 + lq * 8);

    unsigned int e0[8], e1[8];
    #pragma unroll
    for (int jj = 0; jj < 8; ++jj) {
      float asv = (jj < 4) ? as0[jj] : as1[jj - 4];
      float sc0 = asv + ad0;
      float sc1 = asv + ad1;
      sc0 = fmaxf(sc0, 0.2f * sc0);                      // leaky relu
      sc1 = fmaxf(sc1, 0.2f * sc1);
      bool c0 = (word0 >> (lq * 8 + jj)) & 1u;           // adj + self-loop
      bool c1 = (word1 >> (lq * 8 + jj)) & 1u;
      float v0 = c0 ? __expf(sc0) : 0.f;
      float v1 = c1 ? __expf(sc1) : 0.f;
      unsigned int eb0 = __builtin_bit_cast(unsigned int, v0) & 0xffff0000u;
      unsigned int eb1 = __builtin_bit_cast(unsigned int, v1) & 0xffff0000u;
      e0[jj] = eb0;
      e1[jj] = eb1;
      lp0 += __builtin_bit_cast(float, eb0);             // sum the SAME rounded value
      lp1 += __builtin_bit_cast(float, eb1);
    }
    i32x4 p0, p1;
    #pragma unroll
    for (int u = 0; u < 4; ++u) {
      p0[u] = (int)__builtin_amdgcn_perm(e0[2 * u + 1], e0[2 * u], 0x07060302u);
      p1[u] = (int)__builtin_amdgcn_perm(e1[2 * u + 1], e1[2 * u], 0x07060302u);
    }
    s16x8 af0 = __builtin_bit_cast(s16x8, p0);
    s16x8 af1 = __builtin_bit_cast(s16x8, p1);

    acc[0][0] = __builtin_amdgcn_mfma_f32_16x16x32_bf16(af0, b0, acc[0][0], 0, 0, 0);
    acc[0][1] = __builtin_amdgcn_mfma_f32_16x16x32_bf16(af0, b1, acc[0][1], 0, 0, 0);
    acc[0][2] = __builtin_amdgcn_mfma_f32_16x16x32_bf16(af0, b2, acc[0][2], 0, 0, 0);
    acc[0][3] = __builtin_amdgcn_mfma_f32_16x16x32_bf16(af0, b3, acc[0][3], 0, 0, 0);
    acc[1][0] = __builtin_amdgcn_mfma_f32_16x16x32_bf16(af1, b0, acc[1][0], 0, 0, 0);
    acc[1][1] = __builtin_amdgcn_mfma_f32_16x16x32_bf16(af1, b1, acc[1][1], 0, 0, 0);
    acc[1][2] = __builtin_amdgcn_mfma_f32_16x16x32_bf16(af1, b2, acc[1][2], 0, 0, 0);
    acc[1][3] = __builtin_amdgcn_mfma_f32_16x16x32_bf16(af1, b3, acc[1][3], 0, 0, 0);
  }

  // denominators: eighth-row sums for rows lm (sub 0) and 16+lm (sub 1)
  lp0 += __shfl_xor(lp0, 16);
  lp0 += __shfl_xor(lp0, 32);
  lp1 += __shfl_xor(lp1, 16);
  lp1 += __shfl_xor(lp1, 32);
  if (lq == 0) {
    l_lds[jq][lm] = lp0;
    l_lds[jq][16 + lm] = lp1;
  }

  // jq=1..7 park accumulators in LDS (C layout: row=isub*16+lq*4+r, col=lm)
  if (jq != 0) {
    #pragma unroll
    for (int s = 0; s < 2; ++s)
      #pragma unroll
      for (int nf = 0; nf < 4; ++nf)
        #pragma unroll
        for (int r = 0; r < 4; ++r)
          acc_lds[jq - 1][s * 16 + lq * 4 + r][nf * 16 + lm] = acc[s][nf][r];
  }
  __syncthreads();
  if (jq == 0) {
    #pragma unroll
    for (int s = 0; s < 2; ++s) {
      float linv[4];
      #pragma unroll
      for (int r = 0; r < 4; ++r) {
        int row = s * 16 + lq * 4 + r;
        float sum = 0.f;
        #pragma unroll
        for (int q = 0; q < 8; ++q) sum += l_lds[q][row];
        linv[r] = 1.f / sum;
      }
      #pragma unroll
      for (int nf = 0; nf < 4; ++nf) {
        float bia = bias_att[head * 64 + nf * 16 + lm];
        #pragma unroll
        for (int r = 0; r < 4; ++r) {
          int row = s * 16 + lq * 4 + r;
          float v = acc[s][nf][r];
          #pragma unroll
          for (int q = 0; q < 7; ++q) v += acc_lds[q][row][nf * 16 + lm];
          // oS fragment-tile: kp = head*2 + (nf>>1); k%32 = (nf&1)*16 + lm
          size_t idx = (((size_t)((i0 >> 4) + s) * 8) + head * 2 + (nf >> 1)) * 512
                     + (lq * 4 + r) * 32 + (nf & 1) * 16 + lm;
          oS[idx] = f2bf(v * linv[r] + bia);
        }
      }
    }
  }
}

// ---------------- K5: y = oat @ W_out + b_out, then LayerNorm -------------
__global__ __launch_bounds__(256, 2)
void k5_gemm_ln(const ushort_t* __restrict__ oS,     // [256][8][16][32]
                const ushort_t* __restrict__ WoP,    // [8][256][32] k-panels
                const float* __restrict__ b_out,
                const float* __restrict__ gamma,
                const float* __restrict__ beta,
                float* __restrict__ out)
{
  __shared__ float y_lds[16][260];
  const int t = threadIdx.x, lane = t & 63, w = t >> 6;
  const int i0 = blockIdx.x * 16;
  const int lq = lane >> 4, lm = lane & 15;

  f32x4 acc[4];
  #pragma unroll
  for (int nf = 0; nf < 4; ++nf) acc[nf] = f32x4{0.f, 0.f, 0.f, 0.f};

  const ushort_t* oS_b = oS + (size_t)(i0 >> 4) * 4096 + lm * 32 + lq * 8;
  const ushort_t* wp0 = WoP + (size_t)(w * 64 +  0 + lm) * 32 + lq * 8;
  const ushort_t* wp1 = WoP + (size_t)(w * 64 + 16 + lm) * 32 + lq * 8;
  const ushort_t* wp2 = WoP + (size_t)(w * 64 + 32 + lm) * 32 + lq * 8;
  const ushort_t* wp3 = WoP + (size_t)(w * 64 + 48 + lm) * 32 + lq * 8;

  #pragma unroll 2
  for (int kp = 0; kp < 8; ++kp) {
    s16x8 a  = *(const s16x8*)(oS_b + (size_t)kp * 512);
    s16x8 b0 = *(const s16x8*)(wp0 + (size_t)kp * 8192);
    s16x8 b1 = *(const s16x8*)(wp1 + (size_t)kp * 8192);
    s16x8 b2 = *(const s16x8*)(wp2 + (size_t)kp * 8192);
    s16x8 b3 = *(const s16x8*)(wp3 + (size_t)kp * 8192);
    acc[0] = __builtin_amdgcn_mfma_f32_16x16x32_bf16(a, b0, acc[0], 0, 0, 0);
    acc[1] = __builtin_amdgcn_mfma_f32_16x16x32_bf16(a, b1, acc[1], 0, 0, 0);
    acc[2] = __builtin_amdgcn_mfma_f32_16x16x32_bf16(a, b2, acc[2], 0, 0, 0);
    acc[3] = __builtin_amdgcn_mfma_f32_16x16x32_bf16(a, b3, acc[3], 0, 0, 0);
  }
  #pragma unroll
  for (int nf = 0; nf < 4; ++nf)
    #pragma unroll
    for (int r = 0; r < 4; ++r) {
      int row = lq * 4 + r;
      int col = w * 64 + nf * 16 + lm;
      y_lds[row][col] = acc[nf][r] + b_out[col];
    }
  __syncthreads();
  f32x4 g  = *(const f32x4*)(gamma + lane * 4);
  f32x4 be = *(const f32x4*)(beta + lane * 4);
  #pragma unroll
  for (int r = w * 4; r < w * 4 + 4; ++r) {
    f32x4 v = *(const f32x4*)&y_lds[r][lane * 4];
    float s1 = v[0] + v[1] + v[2] + v[3];
    float s2 = v[0]*v[0] + v[1]*v[1] + v[2]*v[2] + v[3]*v[3];
    #pragma unroll
    for (int mm = 1; mm < 64; mm <<= 1) { s1 += __shfl_xor(s1, mm); s2 += __shfl_xor(s2, mm); }
    float mu = s1 * (1.f / 256.f);
    float var = s2 * (1.f / 256.f) - mu * mu;
    float rs = rsqrtf(var + 1e-5f);
    f32x4 o;
    #pragma unroll
    for (int u = 0; u < 4; ++u) o[u] = (v[u] - mu) * rs * g[u] + be[u];
    *(f32x4*)(out + (size_t)(i0 + r) * EMB + lane * 4) = o;
  }
}

extern "C" void kernel_launch(void* const* d_in, const int* in_sizes, int n_in,
                              void* d_out, int out_size, void* d_ws, size_t ws_size,
                              hipStream_t stream)
{
  (void)in_sizes; (void)n_in; (void)out_size; (void)ws_size;
  const float* x        = (const float*)d_in[0];
  const int*   adj      = (const int*)d_in[1];
  const float* W_lin    = (const float*)d_in[2];
  const float* att_src  = (const float*)d_in[3];
  const float* att_dst  = (const float*)d_in[4];
  const float* bias_att = (const float*)d_in[5];
  const float* W_out    = (const float*)d_in[6];
  const float* b_out    = (const float*)d_in[7];
  const float* gamma    = (const float*)d_in[8];
  const float* beta     = (const float*)d_in[9];
  float* out = (float*)d_out;

  uint8_t* p = (uint8_t*)d_ws;
  ushort_t* WlP = (ushort_t*)p;  p += (size_t)EMB * EMB * sizeof(ushort_t);
  ushort_t* WoP = (ushort_t*)p;  p += (size_t)EMB * EMB * sizeof(ushort_t);
  ushort_t* hS  = (ushort_t*)p;  p += (size_t)NH * HC * N * sizeof(ushort_t);
  float* a_srcb = (float*)p;     p += (size_t)NH * N * sizeof(float);
  float* a_dstb = (float*)p;     p += (size_t)NH * N * sizeof(float);
  ushort_t* oS  = (ushort_t*)p;  p += (size_t)N * EMB * sizeof(ushort_t);
  unsigned int* abits = (unsigned int*)p; p += (size_t)(N / 32) * N * sizeof(unsigned int);

  k_prep<<<4096 + 512, 256, 0, stream>>>(W_lin, WlP, W_out, WoP, adj, abits);
  k1_gemm_h<<<dim3(N / 32, NH), 256, 0, stream>>>(x, WlP, att_src, att_dst, hS, a_srcb, a_dstb);
  k34_attn<<<dim3(N / 32, NH), 512, 0, stream>>>(abits, hS, a_srcb, a_dstb, bias_att, oS);
  k5_gemm_ln<<<N / 16, 256, 0, stream>>>(oS, WoP, b_out, gamma, beta, out);
}

// Round 14
// 165.148 us; speedup vs baseline: 1.2383x; 1.0029x over previous
//
#include <hip/hip_runtime.h>
#include <stdint.h>

#define N    4096
#define EMB  256
#define NH   4
#define HC   64     // channels per head
#define PAD  40     // LDS inner stride (elements): 80B = 20 banks -> <=2-way
#define LOG2E 1.4426950408889634f

typedef __attribute__((ext_vector_type(8))) short s16x8;   // 8 bf16 frag
typedef __attribute__((ext_vector_type(4))) short s16x4;
typedef __attribute__((ext_vector_type(4))) float f32x4;
typedef __attribute__((ext_vector_type(4))) int   i32x4;
typedef unsigned short ushort_t;

__device__ __forceinline__ unsigned short f2bf(float f) {
  unsigned int u = __builtin_bit_cast(unsigned int, f);
  u += 0x7fffu + ((u >> 16) & 1u);      // RNE (finite values only)
  return (unsigned short)(u >> 16);
}

// ---------------- K_prep: fused adj-bitmask + weight-transpose -------------
// (R11-proven: one block per adj row, coalesced 16KB row read, shfl merge.)
__global__ __launch_bounds__(256)
void k_prep(const float* __restrict__ W0, ushort_t* __restrict__ WP0,
            const float* __restrict__ W1, ushort_t* __restrict__ WP1,
            const int* __restrict__ adj, unsigned int* __restrict__ abits)
{
  int b = blockIdx.x;
  if (b < 4096) {
    const int i = b;
    const int t = threadIdx.x;
    const int* src = adj + (size_t)i * N + t * 16;
    i32x4 v0 = *(const i32x4*)(src);
    i32x4 v1 = *(const i32x4*)(src + 4);
    i32x4 v2 = *(const i32x4*)(src + 8);
    i32x4 v3 = *(const i32x4*)(src + 12);
    unsigned int m = 0;
    #pragma unroll
    for (int u = 0; u < 4; ++u) {
      m |= (v0[u] != 0 ? 1u : 0u) << u;
      m |= (v1[u] != 0 ? 1u : 0u) << (4 + u);
      m |= (v2[u] != 0 ? 1u : 0u) << (8 + u);
      m |= (v3[u] != 0 ? 1u : 0u) << (12 + u);
    }
    if ((i >> 4) == t) m |= 1u << (i & 15);        // self-loop
    unsigned int partner = __shfl_xor(m, 1);
    if ((t & 1) == 0) {
      unsigned int word = m | (partner << 16);
      abits[(size_t)(t >> 1) * N + i] = word;
    }
  } else {
    b -= 4096;
    int k = b & 255;
    int m = threadIdx.x;
    size_t dst = ((size_t)(k >> 5) * 256 + m) * 32 + (k & 31);
    if (b < 256) WP0[dst] = f2bf(W0[k * EMB + m]);
    else         WP1[dst] = f2bf(W1[k * EMB + m]);
  }
}

// ---------------- K1: h = x @ W_lin (bf16 MFMA), barrier-free K-loop -------
// Epilogue change (R14): a_src/a_dst pre-scaled by log2(e) so k34 uses raw
// v_exp (exp2) — leaky-relu commutes with positive scaling.
__global__ __launch_bounds__(256, 2)
void k1_gemm_h(const float* __restrict__ x,
               const ushort_t* __restrict__ WlP,      // [8][256][32] k-panels
               const float* __restrict__ att_src,     // [4][64]
               const float* __restrict__ att_dst,
               ushort_t* __restrict__ hS,             // [4][128][64][32]
               float* __restrict__ a_srcT,            // [4][4096], x log2e
               float* __restrict__ a_dstT)
{
  __shared__ ushort_t T_lds[64][PAD];   // [c][node 0..31]
  __shared__ float red_lds[2][2][32];   // [src/dst][chalf][node]
  const int t = threadIdx.x;
  const int lane = t & 63;
  const int w = t >> 6;
  const int ihalf = w & 1, chalf = w >> 1;
  const int i0 = blockIdx.x * 32;
  const int head = blockIdx.y;
  const int c0 = head * 64;
  const int lq = lane >> 4, lm = lane & 15;

  f32x4 acc[2];
  acc[0] = f32x4{0.f, 0.f, 0.f, 0.f};
  acc[1] = f32x4{0.f, 0.f, 0.f, 0.f};

  const float* xrow = x + (size_t)(i0 + ihalf * 16 + lm) * EMB + lq * 8;
  const ushort_t* wp0 = WlP + (size_t)(c0 + chalf * 32 + lm) * 32 + lq * 8;
  const ushort_t* wp1 = WlP + (size_t)(c0 + chalf * 32 + 16 + lm) * 32 + lq * 8;

  #pragma unroll 2
  for (int kp = 0; kp < 8; ++kp) {
    f32x4 v0 = *(const f32x4*)(xrow + kp * 32);
    f32x4 v1 = *(const f32x4*)(xrow + kp * 32 + 4);
    s16x8 a;
    a[0]=(short)f2bf(v0[0]); a[1]=(short)f2bf(v0[1]); a[2]=(short)f2bf(v0[2]); a[3]=(short)f2bf(v0[3]);
    a[4]=(short)f2bf(v1[0]); a[5]=(short)f2bf(v1[1]); a[6]=(short)f2bf(v1[2]); a[7]=(short)f2bf(v1[3]);
    s16x8 b0 = *(const s16x8*)(wp0 + (size_t)kp * 8192);
    s16x8 b1 = *(const s16x8*)(wp1 + (size_t)kp * 8192);
    acc[0] = __builtin_amdgcn_mfma_f32_16x16x32_bf16(a, b0, acc[0], 0, 0, 0);
    acc[1] = __builtin_amdgcn_mfma_f32_16x16x32_bf16(a, b1, acc[1], 0, 0, 0);
  }

  float ps[4] = {0.f,0.f,0.f,0.f}, pd[4] = {0.f,0.f,0.f,0.f};
  #pragma unroll
  for (int nf = 0; nf < 2; ++nf) {
    int c = chalf * 32 + nf * 16 + lm;
    float wsv = att_src[c0 + c];
    float wdv = att_dst[c0 + c];
    #pragma unroll
    for (int r = 0; r < 4; ++r) {
      float v = acc[nf][r];                 // D: row=lq*4+r, col=lm
      T_lds[c][ihalf * 16 + lq * 4 + r] = f2bf(v);
      ps[r] += v * wsv;
      pd[r] += v * wdv;
    }
  }
  #pragma unroll
  for (int r = 0; r < 4; ++r) {
    #pragma unroll
    for (int mm = 1; mm < 16; mm <<= 1) {
      ps[r] += __shfl_xor(ps[r], mm);
      pd[r] += __shfl_xor(pd[r], mm);
    }
  }
  if (lm == 0) {
    #pragma unroll
    for (int r = 0; r < 4; ++r) {
      int node = ihalf * 16 + lq * 4 + r;
      red_lds[0][chalf][node] = ps[r];
      red_lds[1][chalf][node] = pd[r];
    }
  }
  __syncthreads();
  if (t < 32) {
    a_srcT[head * N + i0 + t] = (red_lds[0][0][t] + red_lds[0][1][t]) * LOG2E;
    a_dstT[head * N + i0 + t] = (red_lds[1][0][t] + red_lds[1][1][t]) * LOG2E;
  }
  {
    int c = t >> 2, seg = t & 3;
    s16x8 v = *(const s16x8*)&T_lds[c][seg * 8];
    size_t base = (((size_t)head * 128 + (i0 >> 5)) * 64 + c) * 32 + seg * 8;
    *(s16x8*)(hS + base) = v;
  }
}

// ---------------- K34: fused masked-softmax attention, atomic-free ---------
// R14: i-tile 64 per wave (4 A-subtiles share ONE B-frag set) — the validated
// lever (16->32 gave 44->35us). Per iter: 4 abits + 4 independent e-chains +
// 4 B-frags + 16 MFMAs. L2 B-traffic halves to 134MB; 4 e-chains of ILP.
// Block 512 = 8 jq waves, 1 head; grid (N/64, NH) = 256 blocks (1/CU).
// Scores pre-scaled by log2e in k1 -> raw v_exp via __builtin_amdgcn_exp2f
// (deletes 67M v_mul). Epilogue: two passes of 32 rows so LDS stays <64KB.
// (512,1): VGPR cap 256, est ~134 used, no spill. All arrays static-indexed.
__global__ __launch_bounds__(512, 1)
void k34_attn(const unsigned int* __restrict__ abits, // [128 jw][4096 i]
              const ushort_t* __restrict__ hS,        // [4][128][64][32]
              const float* __restrict__ a_srcT,       // [4][4096], x log2e
              const float* __restrict__ a_dstT,       // [4][4096], x log2e
              const float* __restrict__ bias_att,     // [256]
              ushort_t* __restrict__ oS)              // [256][8][16][32]
{
  __shared__ float acc_lds[7][32][65];     // jq=1..7 partials, 32 rows/pass
  __shared__ float l_lds[8][64];

  const int t = threadIdx.x;
  const int lane = t & 63;
  const int jq = t >> 6;           // 0..7 = j-eighth
  const int head = blockIdx.y;
  const int i0 = blockIdx.x * 64;
  const int lm = lane & 15, lq = lane >> 4;

  const float* asrc_h = a_srcT + head * N;
  const ushort_t* hS_h = hS + (size_t)head * 128 * 64 * 32;
  float ad[4];
  #pragma unroll
  for (int s = 0; s < 4; ++s) ad[s] = a_dstT[head * N + i0 + s * 16 + lm];

  f32x4 acc[4][4];
  #pragma unroll
  for (int s = 0; s < 4; ++s)
    #pragma unroll
    for (int nf = 0; nf < 4; ++nf) acc[s][nf] = f32x4{0.f, 0.f, 0.f, 0.f};
  float lp[4] = {0.f, 0.f, 0.f, 0.f};

  #pragma unroll 2
  for (int it = 0; it < 16; ++it) {
    const int jw = jq * 16 + it;               // j-window (32 j's)
    const int jl = jw * 32 + lq * 8;           // this lane's first j

    unsigned int word[4];
    #pragma unroll
    for (int s = 0; s < 4; ++s)
      word[s] = abits[(size_t)jw * N + i0 + s * 16 + lm];
    f32x4 as0 = *(const f32x4*)(asrc_h + jl);
    f32x4 as1 = *(const f32x4*)(asrc_h + jl + 4);

    const ushort_t* tile = hS_h + (size_t)jw * 2048;     // [64 c][32 j]
    s16x8 b0 = *(const s16x8*)(tile + ( 0 + lm) * 32 + lq * 8);
    s16x8 b1 = *(const s16x8*)(tile + (16 + lm) * 32 + lq * 8);
    s16x8 b2 = *(const s16x8*)(tile + (32 + lm) * 32 + lq * 8);
    s16x8 b3 = *(const s16x8*)(tile + (48 + lm) * 32 + lq * 8);

    #pragma unroll
    for (int s = 0; s < 4; ++s) {
      unsigned int e[8];
      #pragma unroll
      for (int jj = 0; jj < 8; ++jj) {
        float asv = (jj < 4) ? as0[jj] : as1[jj - 4];
        float sc = asv + ad[s];
        sc = fmaxf(sc, 0.2f * sc);                       // leaky relu (scaled)
        bool con = (word[s] >> (lq * 8 + jj)) & 1u;      // adj + self-loop
        float v = con ? __builtin_amdgcn_exp2f(sc) : 0.f;
        unsigned int eb = __builtin_bit_cast(unsigned int, v) & 0xffff0000u;
        e[jj] = eb;
        lp[s] += __builtin_bit_cast(float, eb);          // sum SAME rounded val
      }
      i32x4 pk;
      #pragma unroll
      for (int u = 0; u < 4; ++u)
        pk[u] = (int)__builtin_amdgcn_perm(e[2 * u + 1], e[2 * u], 0x07060302u);
      s16x8 af = __builtin_bit_cast(s16x8, pk);
      acc[s][0] = __builtin_amdgcn_mfma_f32_16x16x32_bf16(af, b0, acc[s][0], 0, 0, 0);
      acc[s][1] = __builtin_amdgcn_mfma_f32_16x16x32_bf16(af, b1, acc[s][1], 0, 0, 0);
      acc[s][2] = __builtin_amdgcn_mfma_f32_16x16x32_bf16(af, b2, acc[s][2], 0, 0, 0);
      acc[s][3] = __builtin_amdgcn_mfma_f32_16x16x32_bf16(af, b3, acc[s][3], 0, 0, 0);
    }
  }

  // denominators: eighth-row sums; l_lds[jq][local row]
  #pragma unroll
  for (int s = 0; s < 4; ++s) {
    lp[s] += __shfl_xor(lp[s], 16);
    lp[s] += __shfl_xor(lp[s], 32);
  }
  if (lq == 0) {
    #pragma unroll
    for (int s = 0; s < 4; ++s) l_lds[jq][s * 16 + lm] = lp[s];
  }

  // two-pass reduction: pass p covers rows p*32..p*32+31 (LDS reused)
  #pragma unroll
  for (int pass = 0; pass < 2; ++pass) {
    __syncthreads();               // pass0: pre-write; pass1: prev reads done
    if (jq != 0) {
      #pragma unroll
      for (int s = 0; s < 2; ++s)
        #pragma unroll
        for (int nf = 0; nf < 4; ++nf)
          #pragma unroll
          for (int r = 0; r < 4; ++r)
            acc_lds[jq - 1][s * 16 + lq * 4 + r][nf * 16 + lm] = acc[pass * 2 + s][nf][r];
    }
    __syncthreads();
    if (jq == 0) {
      #pragma unroll
      for (int s = 0; s < 2; ++s) {
        const int sg = pass * 2 + s;
        float linv[4];
        #pragma unroll
        for (int r = 0; r < 4; ++r) {
          int row = sg * 16 + lq * 4 + r;
          float sum = 0.f;
          #pragma unroll
          for (int q = 0; q < 8; ++q) sum += l_lds[q][row];
          linv[r] = 1.f / sum;
        }
        #pragma unroll
        for (int nf = 0; nf < 4; ++nf) {
          float bia = bias_att[head * 64 + nf * 16 + lm];
          #pragma unroll
          for (int r = 0; r < 4; ++r) {
            float v = acc[sg][nf][r];
            #pragma unroll
            for (int q = 0; q < 7; ++q)
              v += acc_lds[q][s * 16 + lq * 4 + r][nf * 16 + lm];
            // oS fragment-tile: kp = head*2 + (nf>>1); k%32 = (nf&1)*16+lm
            size_t idx = (((size_t)((i0 >> 4) + sg) * 8) + head * 2 + (nf >> 1)) * 512
                       + (lq * 4 + r) * 32 + (nf & 1) * 16 + lm;
            oS[idx] = f2bf(v * linv[r] + bia);
          }
        }
      }
    }
  }
}

// ---------------- K5: y = oat @ W_out + b_out, then LayerNorm -------------
__global__ __launch_bounds__(256, 2)
void k5_gemm_ln(const ushort_t* __restrict__ oS,     // [256][8][16][32]
                const ushort_t* __restrict__ WoP,    // [8][256][32] k-panels
                const float* __restrict__ b_out,
                const float* __restrict__ gamma,
                const float* __restrict__ beta,
                float* __restrict__ out)
{
  __shared__ float y_lds[16][260];
  const int t = threadIdx.x, lane = t & 63, w = t >> 6;
  const int i0 = blockIdx.x * 16;
  const int lq = lane >> 4, lm = lane & 15;

  f32x4 acc[4];
  #pragma unroll
  for (int nf = 0; nf < 4; ++nf) acc[nf] = f32x4{0.f, 0.f, 0.f, 0.f};

  const ushort_t* oS_b = oS + (size_t)(i0 >> 4) * 4096 + lm * 32 + lq * 8;
  const ushort_t* wp0 = WoP + (size_t)(w * 64 +  0 + lm) * 32 + lq * 8;
  const ushort_t* wp1 = WoP + (size_t)(w * 64 + 16 + lm) * 32 + lq * 8;
  const ushort_t* wp2 = WoP + (size_t)(w * 64 + 32 + lm) * 32 + lq * 8;
  const ushort_t* wp3 = WoP + (size_t)(w * 64 + 48 + lm) * 32 + lq * 8;

  #pragma unroll 2
  for (int kp = 0; kp < 8; ++kp) {
    s16x8 a  = *(const s16x8*)(oS_b + (size_t)kp * 512);
    s16x8 b0 = *(const s16x8*)(wp0 + (size_t)kp * 8192);
    s16x8 b1 = *(const s16x8*)(wp1 + (size_t)kp * 8192);
    s16x8 b2 = *(const s16x8*)(wp2 + (size_t)kp * 8192);
    s16x8 b3 = *(const s16x8*)(wp3 + (size_t)kp * 8192);
    acc[0] = __builtin_amdgcn_mfma_f32_16x16x32_bf16(a, b0, acc[0], 0, 0, 0);
    acc[1] = __builtin_amdgcn_mfma_f32_16x16x32_bf16(a, b1, acc[1], 0, 0, 0);
    acc[2] = __builtin_amdgcn_mfma_f32_16x16x32_bf16(a, b2, acc[2], 0, 0, 0);
    acc[3] = __builtin_amdgcn_mfma_f32_16x16x32_bf16(a, b3, acc[3], 0, 0, 0);
  }
  #pragma unroll
  for (int nf = 0; nf < 4; ++nf)
    #pragma unroll
    for (int r = 0; r < 4; ++r) {
      int row = lq * 4 + r;
      int col = w * 64 + nf * 16 + lm;
      y_lds[row][col] = acc[nf][r] + b_out[col];
    }
  __syncthreads();
  f32x4 g  = *(const f32x4*)(gamma + lane * 4);
  f32x4 be = *(const f32x4*)(beta + lane * 4);
  #pragma unroll
  for (int r = w * 4; r < w * 4 + 4; ++r) {
    f32x4 v = *(const f32x4*)&y_lds[r][lane * 4];
    float s1 = v[0] + v[1] + v[2] + v[3];
    float s2 = v[0]*v[0] + v[1]*v[1] + v[2]*v[2] + v[3]*v[3];
    #pragma unroll
    for (int mm = 1; mm < 64; mm <<= 1) { s1 += __shfl_xor(s1, mm); s2 += __shfl_xor(s2, mm); }
    float mu = s1 * (1.f / 256.f);
    float var = s2 * (1.f / 256.f) - mu * mu;
    float rs = rsqrtf(var + 1e-5f);
    f32x4 o;
    #pragma unroll
    for (int u = 0; u < 4; ++u) o[u] = (v[u] - mu) * rs * g[u] + be[u];
    *(f32x4*)(out + (size_t)(i0 + r) * EMB + lane * 4) = o;
  }
}

extern "C" void kernel_launch(void* const* d_in, const int* in_sizes, int n_in,
                              void* d_out, int out_size, void* d_ws, size_t ws_size,
                              hipStream_t stream)
{
  (void)in_sizes; (void)n_in; (void)out_size; (void)ws_size;
  const float* x        = (const float*)d_in[0];
  const int*   adj      = (const int*)d_in[1];
  const float* W_lin    = (const float*)d_in[2];
  const float* att_src  = (const float*)d_in[3];
  const float* att_dst  = (const float*)d_in[4];
  const float* bias_att = (const float*)d_in[5];
  const float* W_out    = (const float*)d_in[6];
  const float* b_out    = (const float*)d_in[7];
  const float* gamma    = (const float*)d_in[8];
  const float* beta     = (const float*)d_in[9];
  float* out = (float*)d_out;

  uint8_t* p = (uint8_t*)d_ws;
  ushort_t* WlP = (ushort_t*)p;  p += (size_t)EMB * EMB * sizeof(ushort_t);
  ushort_t* WoP = (ushort_t*)p;  p += (size_t)EMB * EMB * sizeof(ushort_t);
  ushort_t* hS  = (ushort_t*)p;  p += (size_t)NH * HC * N * sizeof(ushort_t);
  float* a_srcb = (float*)p;     p += (size_t)NH * N * sizeof(float);
  float* a_dstb = (float*)p;     p += (size_t)NH * N * sizeof(float);
  ushort_t* oS  = (ushort_t*)p;  p += (size_t)N * EMB * sizeof(ushort_t);
  unsigned int* abits = (unsigned int*)p; p += (size_t)(N / 32) * N * sizeof(unsigned int);

  k_prep<<<4096 + 512, 256, 0, stream>>>(W_lin, WlP, W_out, WoP, adj, abits);
  k1_gemm_h<<<dim3(N / 32, NH), 256, 0, stream>>>(x, WlP, att_src, att_dst, hS, a_srcb, a_dstb);
  k34_attn<<<dim3(N / 64, NH), 512, 0, stream>>>(abits, hS, a_srcb, a_dstb, bias_att, oS);
  k5_gemm_ln<<<N / 16, 256, 0, stream>>>(oS, WoP, b_out, gamma, beta, out);
}